// Round 4
// baseline (2080.576 us; speedup 1.0000x reference)
//
#include <hip/hip_runtime.h>
#include <hip/hip_bf16.h>

#define N_STATE 1024
#define N_HEAD  16
#define D_HEAD  64
#define BATCH   8
#define SEQ     1500
#define ROWS    (BATCH*SEQ)   // 12000

typedef __bf16 bf16x8 __attribute__((ext_vector_type(8)));
typedef float  f32x4  __attribute__((ext_vector_type(4)));

__device__ __forceinline__ f32x4 mfma16(bf16x8 a, bf16x8 b, f32x4 c) {
  return __builtin_amdgcn_mfma_f32_16x16x32_bf16(a, b, c, 0, 0, 0);
}

// Load 8 contiguous elements as bf16x8 from storage that is either bf16 or fp32.
__device__ __forceinline__ bf16x8 load8(const void* p, size_t off, int f32) {
  if (f32) {
    const float* q = (const float*)p + off;
    f32x4 u0 = *(const f32x4*)q;
    f32x4 u1 = *(const f32x4*)(q + 4);
    bf16x8 r;
    r[0] = (__bf16)u0[0]; r[1] = (__bf16)u0[1]; r[2] = (__bf16)u0[2]; r[3] = (__bf16)u0[3];
    r[4] = (__bf16)u1[0]; r[5] = (__bf16)u1[1]; r[6] = (__bf16)u1[2]; r[7] = (__bf16)u1[3];
    return r;
  }
  return *(const bf16x8*)((const __bf16*)p + off);
}

__device__ __forceinline__ float loadS(const void* p, int off, int f32) {
  return f32 ? ((const float*)p)[off] : (float)((const __bf16*)p)[off];
}

// ---------------------------------------------------------------------------
// Input dtype detector: read Wq's first 16384 ushorts AS IF bf16. If storage
// is really fp32, the low-mantissa halves decode to |v|>1e6 / NaN with
// probability ~1 over 8192 samples; genuine bf16 weights are |v|<=0.2.
// flag=1 -> inputs are fp32; flag=0 -> inputs are bf16. Deterministic.
// ---------------------------------------------------------------------------
__global__ __launch_bounds__(64)
void detect_dtype(const void* w, int* flag) {
  const unsigned short* u = (const unsigned short*)w;
  int bad = 0;
  for (int i = threadIdx.x; i < 16384; i += 64) {
    float f = __uint_as_float(((unsigned int)u[i]) << 16);
    if (!(fabsf(f) <= 1.0e6f)) bad = 1;  // catches huge AND NaN/inf
  }
  unsigned long long any = __ballot(bad);
  if (threadIdx.x == 0) *flag = (any != 0ULL) ? 1 : 0;
}

// ---------------------------------------------------------------------------
// QKV projection: C[m,n] = sum_k X[m,k] * W[n,k] (+ bias[n])
// One wave computes a 16(m) x 64(n) tile; blockIdx.z selects q/k/v.
// Outputs bf16 workspace in [B, H, S, D].
// ---------------------------------------------------------------------------
__global__ __launch_bounds__(64)
void qkv_gemm(const void* __restrict__ x,
              const void* __restrict__ Wq, const void* __restrict__ bq,
              const void* __restrict__ Wk,
              const void* __restrict__ Wv, const void* __restrict__ bv,
              __bf16* __restrict__ q_ws, __bf16* __restrict__ k_ws,
              __bf16* __restrict__ v_ws, const int* __restrict__ flag)
{
  const int f32 = *flag;
  const int mt = blockIdx.x, nt = blockIdx.y, which = blockIdx.z;
  const void* W    = (which == 0) ? Wq : (which == 1) ? Wk : Wv;
  const void* bias = (which == 0) ? bq : (which == 2) ? bv : nullptr;
  __bf16* dst      = (which == 0) ? q_ws : (which == 1) ? k_ws : v_ws;

  const int lane = threadIdx.x, l15 = lane & 15, quad = lane >> 4;
  const size_t xbase = (size_t)(mt * 16 + l15) * N_STATE + quad * 8;
  f32x4 acc[4] = {};
  for (int k0 = 0; k0 < N_STATE; k0 += 32) {
    bf16x8 a = load8(x, xbase + k0, f32);
#pragma unroll
    for (int nn = 0; nn < 4; ++nn) {
      const size_t wbase =
          (size_t)(nt * 64 + nn * 16 + l15) * N_STATE + k0 + quad * 8;
      acc[nn] = mfma16(a, load8(W, wbase, f32), acc[nn]);
    }
  }
#pragma unroll
  for (int nn = 0; nn < 4; ++nn) {
    const int col = nt * 64 + nn * 16 + l15;
    const int h = col >> 6, d = col & 63;
    const float badd = bias ? loadS(bias, col, f32) : 0.0f;
#pragma unroll
    for (int r = 0; r < 4; ++r) {
      const int row = mt * 16 + quad * 4 + r;   // C/D: col=lane&15, row=quad*4+r
      const int b = row / SEQ, s = row % SEQ;
      dst[(((size_t)(b * N_HEAD + h)) * SEQ + s) * D_HEAD + d] =
          (__bf16)(acc[nn][r] + badd);
    }
  }
}

// ---------------------------------------------------------------------------
// Flash attention, causal. One wave per (16-query tile, b*H+h). bf16 ws only.
// NaN-hardened: -1e30 sentinel instead of -inf (no inf-inf path possible).
// ---------------------------------------------------------------------------
__global__ __launch_bounds__(64)
void flash_attn(const __bf16* __restrict__ q_ws, const __bf16* __restrict__ k_ws,
                const __bf16* __restrict__ v_ws, __bf16* __restrict__ attn)
{
  __shared__ __align__(16) __bf16 lds_p[16 * 32];
  const int qt = blockIdx.x, bh = blockIdx.y;
  const int lane = threadIdx.x, l15 = lane & 15, quad = lane >> 4;
  const __bf16* Q = q_ws + (size_t)bh * SEQ * D_HEAD;
  const __bf16* K = k_ws + (size_t)bh * SEQ * D_HEAD;
  const __bf16* V = v_ws + (size_t)bh * SEQ * D_HEAD;
  const int q0 = qt * 16;
  const int qload = min(q0 + l15, SEQ - 1);
  const bf16x8 qa0 = *(const bf16x8*)(Q + qload * D_HEAD + quad * 8);
  const bf16x8 qa1 = *(const bf16x8*)(Q + qload * D_HEAD + 32 + quad * 8);

  const float NEG = -1.0e30f;
  f32x4 o[4] = {};
  float m_i[4], l_i[4];
#pragma unroll
  for (int r = 0; r < 4; ++r) { m_i[r] = NEG; l_i[r] = 0.0f; }
  const float scale = 0.125f;  // 1/sqrt(64)
  const int qmax = q0 + 15;

  for (int kt = 0; kt <= qmax && kt < SEQ; kt += 32) {
    const int krow0 = kt + l15, krow1 = kt + 16 + l15;
    const int kr0 = min(krow0, SEQ - 1), kr1 = min(krow1, SEQ - 1);
    f32x4 s0 = {}, s1 = {};
    s0 = mfma16(qa0, *(const bf16x8*)(K + kr0 * D_HEAD + quad * 8), s0);
    s0 = mfma16(qa1, *(const bf16x8*)(K + kr0 * D_HEAD + 32 + quad * 8), s0);
    s1 = mfma16(qa0, *(const bf16x8*)(K + kr1 * D_HEAD + quad * 8), s1);
    s1 = mfma16(qa1, *(const bf16x8*)(K + kr1 * D_HEAD + 32 + quad * 8), s1);

    float alpha[4], p0[4], p1[4];
#pragma unroll
    for (int r = 0; r < 4; ++r) {
      const int qr = q0 + quad * 4 + r;  // logical query row of this C-slot
      float v0 = (krow0 <= qr && krow0 < SEQ) ? s0[r] * scale : NEG;
      float v1 = (krow1 <= qr && krow1 < SEQ) ? s1[r] * scale : NEG;
      float tmax = fmaxf(v0, v1);
#pragma unroll
      for (int off = 1; off < 16; off <<= 1)
        tmax = fmaxf(tmax, __shfl_xor(tmax, off));
      const float mnew = fmaxf(m_i[r], tmax);  // finite always (key 0 in tile 0)
      alpha[r] = __expf(m_i[r] - mnew);
      const float e0 = __expf(v0 - mnew);
      const float e1 = __expf(v1 - mnew);
      float rsum = e0 + e1;
#pragma unroll
      for (int off = 1; off < 16; off <<= 1)
        rsum += __shfl_xor(rsum, off);
      l_i[r] = l_i[r] * alpha[r] + rsum;
      m_i[r] = mnew;
      p0[r] = e0; p1[r] = e1;
    }
#pragma unroll
    for (int nn = 0; nn < 4; ++nn)
#pragma unroll
      for (int r = 0; r < 4; ++r) o[nn][r] *= alpha[r];

    // P: C-layout (row=quad*4+r, col=l15 / 16+l15) -> LDS [query][key_local]
#pragma unroll
    for (int r = 0; r < 4; ++r) {
      lds_p[(quad * 4 + r) * 32 + l15]      = (__bf16)p0[r];
      lds_p[(quad * 4 + r) * 32 + 16 + l15] = (__bf16)p1[r];
    }
    __syncthreads();
    const bf16x8 pa = *(const bf16x8*)(&lds_p[l15 * 32 + quad * 8]);  // A-layout
#pragma unroll
    for (int nn = 0; nn < 4; ++nn) {
      bf16x8 vb;  // B-frag: V[k=kt+quad*8+j][n=nn*16+l15]
#pragma unroll
      for (int j = 0; j < 8; ++j) {
        const int vr = min(kt + quad * 8 + j, SEQ - 1);  // p=0 masks OOB rows
        vb[j] = V[vr * D_HEAD + nn * 16 + l15];
      }
      o[nn] = mfma16(pa, vb, o[nn]);
    }
    __syncthreads();
  }

  const int b = bh >> 4, h = bh & 15;
#pragma unroll
  for (int r = 0; r < 4; ++r) {
    const int qr = q0 + quad * 4 + r;
    if (qr < SEQ) {
      const float inv = 1.0f / l_i[r];   // l_i >= 1 for valid rows
#pragma unroll
      for (int nn = 0; nn < 4; ++nn) {
        attn[(((size_t)(b * SEQ + qr)) * N_HEAD + h) * D_HEAD + nn * 16 + l15] =
            (__bf16)(o[nn][r] * inv);
      }
    }
  }
}

// ---------------------------------------------------------------------------
// Output projection: out = attn @ Wo^T + bo. attn ws is bf16; Wo/bo/out
// follow the detected dtype.
// ---------------------------------------------------------------------------
__global__ __launch_bounds__(64)
void out_gemm(const __bf16* __restrict__ a_in, const void* __restrict__ Wo,
              const void* __restrict__ bo, void* __restrict__ out,
              const int* __restrict__ flag)
{
  const int f32 = *flag;
  const int mt = blockIdx.x, nt = blockIdx.y;
  const int lane = threadIdx.x, l15 = lane & 15, quad = lane >> 4;
  const __bf16* arow = a_in + (size_t)(mt * 16 + l15) * N_STATE + quad * 8;
  f32x4 acc[4] = {};
  for (int k0 = 0; k0 < N_STATE; k0 += 32) {
    bf16x8 a = *(const bf16x8*)(arow + k0);
#pragma unroll
    for (int nn = 0; nn < 4; ++nn) {
      const size_t wbase =
          (size_t)(nt * 64 + nn * 16 + l15) * N_STATE + k0 + quad * 8;
      acc[nn] = mfma16(a, load8(Wo, wbase, f32), acc[nn]);
    }
  }
#pragma unroll
  for (int nn = 0; nn < 4; ++nn) {
    const int col = nt * 64 + nn * 16 + l15;
    const float badd = loadS(bo, col, f32);
#pragma unroll
    for (int r = 0; r < 4; ++r) {
      const int row = mt * 16 + quad * 4 + r;
      const float v = acc[nn][r] + badd;
      const size_t idx = (size_t)row * N_STATE + col;
      if (f32) ((float*)out)[idx] = v;
      else     ((__bf16*)out)[idx] = (__bf16)v;
    }
  }
}

// ---------------------------------------------------------------------------
extern "C" void kernel_launch(void* const* d_in, const int* in_sizes, int n_in,
                              void* d_out, int out_size, void* d_ws, size_t ws_size,
                              hipStream_t stream) {
  const void* x  = d_in[0];
  // d_in[1] = mask: causal, implemented analytically — not read.
  const void* Wq = d_in[2];
  const void* bq = d_in[3];
  const void* Wk = d_in[4];
  const void* Wv = d_in[5];
  const void* bv = d_in[6];
  const void* Wo = d_in[7];
  const void* bo = d_in[8];

  // ws layout: [flag header 16 B][q][k][v][attn], chunks bf16 [ROWS*N_STATE].
  // Round-3 NaN propagation through the full chain proved ws_size >= 98.3 MB.
  const size_t chunk = (size_t)ROWS * N_STATE;
  int*    flag = (int*)d_ws;
  __bf16* q_ws = (__bf16*)((char*)d_ws + 16);
  __bf16* k_ws = q_ws + chunk;
  __bf16* v_ws = k_ws + chunk;
  __bf16* attn = v_ws + chunk;

  detect_dtype<<<1, 64, 0, stream>>>(Wq, flag);
  qkv_gemm<<<dim3(ROWS / 16, N_STATE / 64, 3), 64, 0, stream>>>(
      x, Wq, bq, Wk, Wv, bv, q_ws, k_ws, v_ws, flag);
  flash_attn<<<dim3((SEQ + 15) / 16, BATCH * N_HEAD), 64, 0, stream>>>(
      q_ws, k_ws, v_ws, attn);
  out_gemm<<<dim3(ROWS / 16, N_STATE / 64), 64, 0, stream>>>(attn, Wo, bo, d_out, flag);
}

// Round 5
// 615.255 us; speedup vs baseline: 3.3816x; 3.3816x over previous
//
#include <hip/hip_runtime.h>
#include <hip/hip_bf16.h>

#define N_STATE 1024
#define N_HEAD  16
#define D_HEAD  64
#define BATCH   8
#define SEQ     1500
#define ROWS    (BATCH*SEQ)   // 12000

#define BM 128
#define BN 128
#define BK 32

typedef __bf16 bf16x8 __attribute__((ext_vector_type(8)));
typedef __bf16 bf16x4 __attribute__((ext_vector_type(4)));
typedef float  f32x4  __attribute__((ext_vector_type(4)));

__device__ __forceinline__ f32x4 mfma16(bf16x8 a, bf16x8 b, f32x4 c) {
  return __builtin_amdgcn_mfma_f32_16x16x32_bf16(a, b, c, 0, 0, 0);
}

// ---------------------------------------------------------------------------
// Tiled QKV projection (inputs fp32 — proven in round 4).
// Block = 256 thr (4 waves, 2x2), tile 128x128, BK=32, bf16 LDS staging.
// C[m,n] = sum_k X[m,k]*W[n,k] + bias[n]; W stored [out,in] == B^T.
// Output bf16 workspace in [B, H, S, D].
// ---------------------------------------------------------------------------
__global__ __launch_bounds__(256)
void qkv_gemm(const float* __restrict__ x,
              const float* __restrict__ Wq, const float* __restrict__ bq,
              const float* __restrict__ Wk,
              const float* __restrict__ Wv, const float* __restrict__ bv,
              __bf16* __restrict__ q_ws, __bf16* __restrict__ k_ws,
              __bf16* __restrict__ v_ws)
{
  __shared__ __bf16 lA[BM * BK];   // [row][k], stride 32 (m97 layout)
  __shared__ __bf16 lB[BN * BK];
  const int which = blockIdx.z;
  const float* W    = (which == 0) ? Wq : (which == 1) ? Wk : Wv;
  const float* bias = (which == 0) ? bq : (which == 2) ? bv : nullptr;
  __bf16* dst       = (which == 0) ? q_ws : (which == 1) ? k_ws : v_ws;

  const int mt = blockIdx.x, nt = blockIdx.y;
  const int tid = threadIdx.x;
  const int lane = tid & 63, wave = tid >> 6;
  const int l15 = lane & 15, quad = lane >> 4;
  const int wr = wave >> 1, wc = wave & 1;   // 2x2 wave grid, 64x64 each

  f32x4 acc[4][4] = {};

  for (int k0 = 0; k0 < N_STATE; k0 += BK) {
    // --- stage A (x rows) and B (W rows) : fp32 -> bf16 -> LDS ---
#pragma unroll
    for (int it = 0; it < 4; ++it) {
      const int s = tid + it * 256;        // 1024 float4-slots per 128x32 tile
      const int row = s >> 3, seg = s & 7; // 8 x float4 per row
      const int ga = min(mt * BM + row, ROWS - 1);           // clamp M tail
      const f32x4 va = *(const f32x4*)(x + (size_t)ga * N_STATE + k0 + seg * 4);
      bf16x4 ca; ca[0]=(__bf16)va[0]; ca[1]=(__bf16)va[1];
                 ca[2]=(__bf16)va[2]; ca[3]=(__bf16)va[3];
      *(bf16x4*)&lA[row * BK + seg * 4] = ca;
      const int gb = nt * BM + row;                          // 0..1023, exact
      const f32x4 vb = *(const f32x4*)(W + (size_t)gb * N_STATE + k0 + seg * 4);
      bf16x4 cb; cb[0]=(__bf16)vb[0]; cb[1]=(__bf16)vb[1];
                 cb[2]=(__bf16)vb[2]; cb[3]=(__bf16)vb[3];
      *(bf16x4*)&lB[row * BK + seg * 4] = cb;
    }
    __syncthreads();
    // --- fragments + 16 MFMA ---
    bf16x8 af[4], bfr[4];
#pragma unroll
    for (int i = 0; i < 4; ++i) {
      af[i]  = *(const bf16x8*)&lA[(wr * 64 + i * 16 + l15) * BK + quad * 8];
      bfr[i] = *(const bf16x8*)&lB[(wc * 64 + i * 16 + l15) * BK + quad * 8];
    }
#pragma unroll
    for (int i = 0; i < 4; ++i)
#pragma unroll
      for (int j = 0; j < 4; ++j)
        acc[i][j] = mfma16(af[i], bfr[j], acc[i][j]);
    __syncthreads();
  }

  // --- epilogue: bias + scatter to [B,H,S,D] bf16 ---
#pragma unroll
  for (int i = 0; i < 4; ++i) {
    const int mrow = mt * BM + wr * 64 + i * 16 + quad * 4;
#pragma unroll
    for (int j = 0; j < 4; ++j) {
      const int col = nt * BN + wc * 64 + j * 16 + l15;
      const int h = col >> 6, d = col & 63;
      const float badd = bias ? bias[col] : 0.0f;
#pragma unroll
      for (int r = 0; r < 4; ++r) {
        const int row = mrow + r;          // C/D: col=lane&15, row=quad*4+r
        if (row < ROWS) {
          const int b = row / SEQ, s = row % SEQ;
          dst[(((size_t)(b * N_HEAD + h)) * SEQ + s) * D_HEAD + d] =
              (__bf16)(acc[i][j][r] + badd);
        }
      }
    }
  }
}

// ---------------------------------------------------------------------------
// Flash attention, causal — UNCHANGED from validated round-4 kernel.
// One wave per (16-query tile, b*H+h); bf16 workspace.
// ---------------------------------------------------------------------------
__global__ __launch_bounds__(64)
void flash_attn(const __bf16* __restrict__ q_ws, const __bf16* __restrict__ k_ws,
                const __bf16* __restrict__ v_ws, __bf16* __restrict__ attn)
{
  __shared__ __align__(16) __bf16 lds_p[16 * 32];
  const int qt = blockIdx.x, bh = blockIdx.y;
  const int lane = threadIdx.x, l15 = lane & 15, quad = lane >> 4;
  const __bf16* Q = q_ws + (size_t)bh * SEQ * D_HEAD;
  const __bf16* K = k_ws + (size_t)bh * SEQ * D_HEAD;
  const __bf16* V = v_ws + (size_t)bh * SEQ * D_HEAD;
  const int q0 = qt * 16;
  const int qload = min(q0 + l15, SEQ - 1);
  const bf16x8 qa0 = *(const bf16x8*)(Q + qload * D_HEAD + quad * 8);
  const bf16x8 qa1 = *(const bf16x8*)(Q + qload * D_HEAD + 32 + quad * 8);

  const float NEG = -1.0e30f;
  f32x4 o[4] = {};
  float m_i[4], l_i[4];
#pragma unroll
  for (int r = 0; r < 4; ++r) { m_i[r] = NEG; l_i[r] = 0.0f; }
  const float scale = 0.125f;  // 1/sqrt(64)
  const int qmax = q0 + 15;

  for (int kt = 0; kt <= qmax && kt < SEQ; kt += 32) {
    const int krow0 = kt + l15, krow1 = kt + 16 + l15;
    const int kr0 = min(krow0, SEQ - 1), kr1 = min(krow1, SEQ - 1);
    f32x4 s0 = {}, s1 = {};
    s0 = mfma16(qa0, *(const bf16x8*)(K + kr0 * D_HEAD + quad * 8), s0);
    s0 = mfma16(qa1, *(const bf16x8*)(K + kr0 * D_HEAD + 32 + quad * 8), s0);
    s1 = mfma16(qa0, *(const bf16x8*)(K + kr1 * D_HEAD + quad * 8), s1);
    s1 = mfma16(qa1, *(const bf16x8*)(K + kr1 * D_HEAD + 32 + quad * 8), s1);

    float alpha[4], p0[4], p1[4];
#pragma unroll
    for (int r = 0; r < 4; ++r) {
      const int qr = q0 + quad * 4 + r;
      float v0 = (krow0 <= qr && krow0 < SEQ) ? s0[r] * scale : NEG;
      float v1 = (krow1 <= qr && krow1 < SEQ) ? s1[r] * scale : NEG;
      float tmax = fmaxf(v0, v1);
#pragma unroll
      for (int off = 1; off < 16; off <<= 1)
        tmax = fmaxf(tmax, __shfl_xor(tmax, off));
      const float mnew = fmaxf(m_i[r], tmax);
      alpha[r] = __expf(m_i[r] - mnew);
      const float e0 = __expf(v0 - mnew);
      const float e1 = __expf(v1 - mnew);
      float rsum = e0 + e1;
#pragma unroll
      for (int off = 1; off < 16; off <<= 1)
        rsum += __shfl_xor(rsum, off);
      l_i[r] = l_i[r] * alpha[r] + rsum;
      m_i[r] = mnew;
      p0[r] = e0; p1[r] = e1;
    }
#pragma unroll
    for (int nn = 0; nn < 4; ++nn)
#pragma unroll
      for (int r = 0; r < 4; ++r) o[nn][r] *= alpha[r];

#pragma unroll
    for (int r = 0; r < 4; ++r) {
      lds_p[(quad * 4 + r) * 32 + l15]      = (__bf16)p0[r];
      lds_p[(quad * 4 + r) * 32 + 16 + l15] = (__bf16)p1[r];
    }
    __syncthreads();
    const bf16x8 pa = *(const bf16x8*)(&lds_p[l15 * 32 + quad * 8]);
#pragma unroll
    for (int nn = 0; nn < 4; ++nn) {
      bf16x8 vb;
#pragma unroll
      for (int j = 0; j < 8; ++j) {
        const int vr = min(kt + quad * 8 + j, SEQ - 1);
        vb[j] = V[vr * D_HEAD + nn * 16 + l15];
      }
      o[nn] = mfma16(pa, vb, o[nn]);
    }
    __syncthreads();
  }

  const int b = bh >> 4, h = bh & 15;
#pragma unroll
  for (int r = 0; r < 4; ++r) {
    const int qr = q0 + quad * 4 + r;
    if (qr < SEQ) {
      const float inv = 1.0f / l_i[r];
#pragma unroll
      for (int nn = 0; nn < 4; ++nn) {
        attn[(((size_t)(b * SEQ + qr)) * N_HEAD + h) * D_HEAD + nn * 16 + l15] =
            (__bf16)(o[nn][r] * inv);
      }
    }
  }
}

// ---------------------------------------------------------------------------
// Tiled output projection: out(fp32) = attn(bf16) @ Wo^T(fp32) + bo.
// Same 128x128 structure; A staged as bf16 directly, B converted.
// ---------------------------------------------------------------------------
__global__ __launch_bounds__(256)
void out_gemm(const __bf16* __restrict__ a_in, const float* __restrict__ Wo,
              const float* __restrict__ bo, float* __restrict__ out)
{
  __shared__ __bf16 lA[BM * BK];
  __shared__ __bf16 lB[BN * BK];
  const int mt = blockIdx.x, nt = blockIdx.y;
  const int tid = threadIdx.x;
  const int lane = tid & 63, wave = tid >> 6;
  const int l15 = lane & 15, quad = lane >> 4;
  const int wr = wave >> 1, wc = wave & 1;

  f32x4 acc[4][4] = {};

  for (int k0 = 0; k0 < N_STATE; k0 += BK) {
    // A: bf16 source, direct 16B copies (512 slots of bf16x8)
#pragma unroll
    for (int it = 0; it < 2; ++it) {
      const int s = tid + it * 256;
      const int row = s >> 2, seg = s & 3;   // 4 x bf16x8 per row
      const int ga = min(mt * BM + row, ROWS - 1);
      *(bf16x8*)&lA[row * BK + seg * 8] =
          *(const bf16x8*)(a_in + (size_t)ga * N_STATE + k0 + seg * 8);
    }
    // B: fp32 -> bf16 (1024 float4 slots)
#pragma unroll
    for (int it = 0; it < 4; ++it) {
      const int s = tid + it * 256;
      const int row = s >> 3, seg = s & 7;
      const int gb = nt * BM + row;
      const f32x4 vb = *(const f32x4*)(Wo + (size_t)gb * N_STATE + k0 + seg * 4);
      bf16x4 cb; cb[0]=(__bf16)vb[0]; cb[1]=(__bf16)vb[1];
                 cb[2]=(__bf16)vb[2]; cb[3]=(__bf16)vb[3];
      *(bf16x4*)&lB[row * BK + seg * 4] = cb;
    }
    __syncthreads();
    bf16x8 af[4], bfr[4];
#pragma unroll
    for (int i = 0; i < 4; ++i) {
      af[i]  = *(const bf16x8*)&lA[(wr * 64 + i * 16 + l15) * BK + quad * 8];
      bfr[i] = *(const bf16x8*)&lB[(wc * 64 + i * 16 + l15) * BK + quad * 8];
    }
#pragma unroll
    for (int i = 0; i < 4; ++i)
#pragma unroll
      for (int j = 0; j < 4; ++j)
        acc[i][j] = mfma16(af[i], bfr[j], acc[i][j]);
    __syncthreads();
  }

#pragma unroll
  for (int i = 0; i < 4; ++i) {
    const int mrow = mt * BM + wr * 64 + i * 16 + quad * 4;
#pragma unroll
    for (int j = 0; j < 4; ++j) {
      const int col = nt * BN + wc * 64 + j * 16 + l15;
      const float badd = bo[col];
#pragma unroll
      for (int r = 0; r < 4; ++r) {
        const int row = mrow + r;
        if (row < ROWS)
          out[(size_t)row * N_STATE + col] = acc[i][j][r] + badd;
      }
    }
  }
}

// ---------------------------------------------------------------------------
extern "C" void kernel_launch(void* const* d_in, const int* in_sizes, int n_in,
                              void* d_out, int out_size, void* d_ws, size_t ws_size,
                              hipStream_t stream) {
  const float* x  = (const float*)d_in[0];
  // d_in[1] = mask: causal, implemented analytically — not read.
  const float* Wq = (const float*)d_in[2];
  const float* bq = (const float*)d_in[3];
  const float* Wk = (const float*)d_in[4];
  const float* Wv = (const float*)d_in[5];
  const float* bv = (const float*)d_in[6];
  const float* Wo = (const float*)d_in[7];
  const float* bo = (const float*)d_in[8];
  float* out = (float*)d_out;

  // ws: 4 bf16 chunks [ROWS*N_STATE] = 98.3 MB (q,k,v in [B,H,S,D]; attn [B,S,H,D])
  const size_t chunk = (size_t)ROWS * N_STATE;
  __bf16* q_ws = (__bf16*)d_ws;
  __bf16* k_ws = q_ws + chunk;
  __bf16* v_ws = k_ws + chunk;
  __bf16* attn = v_ws + chunk;

  const int MT = (ROWS + BM - 1) / BM;   // 94
  qkv_gemm<<<dim3(MT, N_STATE / BN, 3), 256, 0, stream>>>(
      x, Wq, bq, Wk, Wv, bv, q_ws, k_ws, v_ws);
  flash_attn<<<dim3((SEQ + 15) / 16, BATCH * N_HEAD), 64, 0, stream>>>(
      q_ws, k_ws, v_ws, attn);
  out_gemm<<<dim3(MT, N_STATE / BN), 256, 0, stream>>>(attn, Wo, bo, out);
}

// Round 6
// 602.657 us; speedup vs baseline: 3.4523x; 1.0209x over previous
//
#include <hip/hip_runtime.h>
#include <hip/hip_bf16.h>

#define N_STATE 1024
#define N_HEAD  16
#define D_HEAD  64
#define BATCH   8
#define SEQ     1500
#define ROWS    (BATCH*SEQ)   // 12000
#define SVP     1536          // padded seq stride for V^T (16B-aligned rows)

#define BM 128
#define BN 128
#define BK 32

typedef __bf16 bf16x8 __attribute__((ext_vector_type(8)));
typedef __bf16 bf16x4 __attribute__((ext_vector_type(4)));
typedef float  f32x4  __attribute__((ext_vector_type(4)));

__device__ __forceinline__ f32x4 mfma16(bf16x8 a, bf16x8 b, f32x4 c) {
  return __builtin_amdgcn_mfma_f32_16x16x32_bf16(a, b, c, 0, 0, 0);
}

// ---------------------------------------------------------------------------
// Tiled QKV projection (fp32 inputs). 128x128 tile, BK=32, 4 waves.
// which==0/1 (Q,K): C[m,n] stored [B,H,S,D].
// which==2 (V):     C^T computed directly (A=W, B=X -> D[m=dim][n=seq]),
//                   stored transposed [B,H,D,SVP] for vectorized PV in flash.
// ---------------------------------------------------------------------------
__global__ __launch_bounds__(256)
void qkv_gemm(const float* __restrict__ x,
              const float* __restrict__ Wq, const float* __restrict__ bq,
              const float* __restrict__ Wk,
              const float* __restrict__ Wv, const float* __restrict__ bv,
              __bf16* __restrict__ q_ws, __bf16* __restrict__ k_ws,
              __bf16* __restrict__ vt_ws)
{
  __shared__ __bf16 lA[BM * BK];
  __shared__ __bf16 lB[BN * BK];
  const int which = blockIdx.z;
  const float* W    = (which == 0) ? Wq : (which == 1) ? Wk : Wv;
  const float* bias = (which == 0) ? bq : (which == 2) ? bv : nullptr;

  const int mt = blockIdx.x, nt = blockIdx.y;
  const int tid = threadIdx.x;
  const int lane = tid & 63, wave = tid >> 6;
  const int l15 = lane & 15, quad = lane >> 4;
  const int wr = wave >> 1, wc = wave & 1;

  f32x4 acc[4][4] = {};

  for (int k0 = 0; k0 < N_STATE; k0 += BK) {
#pragma unroll
    for (int it = 0; it < 4; ++it) {
      const int s = tid + it * 256;
      const int row = s >> 3, seg = s & 7;
      const int ga = min(mt * BM + row, ROWS - 1);
      const f32x4 va = *(const f32x4*)(x + (size_t)ga * N_STATE + k0 + seg * 4);
      bf16x4 ca; ca[0]=(__bf16)va[0]; ca[1]=(__bf16)va[1];
                 ca[2]=(__bf16)va[2]; ca[3]=(__bf16)va[3];
      *(bf16x4*)&lA[row * BK + seg * 4] = ca;
      const int gb = nt * BM + row;
      const f32x4 vb = *(const f32x4*)(W + (size_t)gb * N_STATE + k0 + seg * 4);
      bf16x4 cb; cb[0]=(__bf16)vb[0]; cb[1]=(__bf16)vb[1];
                 cb[2]=(__bf16)vb[2]; cb[3]=(__bf16)vb[3];
      *(bf16x4*)&lB[row * BK + seg * 4] = cb;
    }
    __syncthreads();
    bf16x8 af[4], bfr[4];
#pragma unroll
    for (int i = 0; i < 4; ++i) {
      af[i]  = *(const bf16x8*)&lA[(wr * 64 + i * 16 + l15) * BK + quad * 8];
      bfr[i] = *(const bf16x8*)&lB[(wc * 64 + i * 16 + l15) * BK + quad * 8];
    }
    if (which != 2) {
#pragma unroll
      for (int i = 0; i < 4; ++i)
#pragma unroll
        for (int j = 0; j < 4; ++j)
          acc[i][j] = mfma16(af[i], bfr[j], acc[i][j]);
    } else {
      // swapped operands: D[m=W-row(dim)][n=X-row(seq)] = C^T
#pragma unroll
      for (int i = 0; i < 4; ++i)
#pragma unroll
        for (int j = 0; j < 4; ++j)
          acc[i][j] = mfma16(bfr[j], af[i], acc[i][j]);
    }
    __syncthreads();
  }

  if (which != 2) {
#pragma unroll
    for (int i = 0; i < 4; ++i) {
      const int mrow = mt * BM + wr * 64 + i * 16 + quad * 4;
#pragma unroll
      for (int j = 0; j < 4; ++j) {
        const int col = nt * BN + wc * 64 + j * 16 + l15;
        const int h = col >> 6, d = col & 63;
        const float badd = bias ? bias[col] : 0.0f;
        __bf16* dst = (which == 0) ? q_ws : k_ws;
#pragma unroll
        for (int r = 0; r < 4; ++r) {
          const int row = mrow + r;
          if (row < ROWS) {
            const int b = row / SEQ, s = row % SEQ;
            dst[(((size_t)(b * N_HEAD + h)) * SEQ + s) * D_HEAD + d] =
                (__bf16)(acc[i][j][r] + badd);
          }
        }
      }
    }
  } else {
    // C^T epilogue: lane col (l15) = seq-row (contiguous stores), reg = dim.
#pragma unroll
    for (int i = 0; i < 4; ++i) {
      const int sg = mt * BM + wr * 64 + i * 16 + l15;   // global seq-row
      const bool valid = sg < ROWS;
      const int b = sg / SEQ, srow = sg % SEQ;
#pragma unroll
      for (int j = 0; j < 4; ++j) {
        const int dbase = nt * BN + wc * 64 + j * 16 + quad * 4;  // global dim
#pragma unroll
        for (int r = 0; r < 4; ++r) {
          const int d = dbase + r;
          const int h = d >> 6, dd = d & 63;
          if (valid)
            vt_ws[(((size_t)(b * N_HEAD + h)) * D_HEAD + dd) * SVP + srow] =
                (__bf16)(acc[i][j][r] + bias[d]);
        }
      }
    }
  }
}

// ---------------------------------------------------------------------------
// Flash attention v2, causal. Block = 4 waves, 64 queries; 64-key LDS tiles.
// K: [S][64] staged to lK[64][72]; V^T: [64][SVP] staged to lV[64][72].
// Stride-72 rows (144 B == 16 mod 128) -> conflict-free b128 LDS access.
// Grid: x=bh (XCD-pinned, 128 = 16 heads x 8 XCDs), y=qt reversed (big first).
// ---------------------------------------------------------------------------
__global__ __launch_bounds__(256)
void flash_attn(const __bf16* __restrict__ q_ws, const __bf16* __restrict__ k_ws,
                const __bf16* __restrict__ vt_ws, __bf16* __restrict__ attn)
{
  __shared__ __bf16 lK[64 * 72];
  __shared__ __bf16 lV[64 * 72];
  __shared__ __bf16 lP[4 * 16 * 72];
  const int bh = blockIdx.x;
  const int qt = gridDim.y - 1 - blockIdx.y;   // heavy tiles first
  const int tid = threadIdx.x, lane = tid & 63, wave = tid >> 6;
  const int l15 = lane & 15, quad = lane >> 4;
  const __bf16* Q  = q_ws  + (size_t)bh * SEQ * D_HEAD;
  const __bf16* K  = k_ws  + (size_t)bh * SEQ * D_HEAD;
  const __bf16* Vt = vt_ws + (size_t)bh * D_HEAD * SVP;
  __bf16* lPw = lP + wave * 16 * 72;

  const int q0 = qt * 64, wq0 = q0 + wave * 16;
  const int qload = min(wq0 + l15, SEQ - 1);
  const bf16x8 qa0 = *(const bf16x8*)(Q + (size_t)qload * D_HEAD + quad * 8);
  const bf16x8 qa1 = *(const bf16x8*)(Q + (size_t)qload * D_HEAD + 32 + quad * 8);

  const float NEG = -1.0e30f;
  const float scale = 0.125f;
  f32x4 o[4] = {};
  float m_i[4], l_i[4];
#pragma unroll
  for (int r = 0; r < 4; ++r) { m_i[r] = NEG; l_i[r] = 0.0f; }

  const int kmax = min(q0 + 63, SEQ - 1);
  const int wqmax = wq0 + 15;

  for (int kt = 0; kt <= kmax; kt += 64) {
    // ---- cooperative staging: K rows + V^T rows (both vector b128) ----
#pragma unroll
    for (int it = 0; it < 2; ++it) {
      const int s = tid + it * 256;
      const int row = s >> 3, seg = s & 7;
      const int gk = min(kt + row, SEQ - 1);
      *(bf16x8*)&lK[row * 72 + seg * 8] =
          *(const bf16x8*)(K + (size_t)gk * D_HEAD + seg * 8);
      *(bf16x8*)&lV[row * 72 + seg * 8] =
          *(const bf16x8*)(Vt + (size_t)row * SVP + kt + seg * 8);
    }
    __syncthreads();

    if (kt <= wqmax) {
      // ---- QK^T: 4 key-groups x 2 d-halves = 8 MFMAs ----
      f32x4 sg[4] = {};
#pragma unroll
      for (int g = 0; g < 4; ++g) {
        const __bf16* kr = &lK[(g * 16 + l15) * 72 + quad * 8];
        sg[g] = mfma16(qa0, *(const bf16x8*)kr, sg[g]);
        sg[g] = mfma16(qa1, *(const bf16x8*)(kr + 32), sg[g]);
      }
      const bool fullvis = (kt + 63 <= wq0) && (kt + 63 < SEQ);
      float alpha[4];
#pragma unroll
      for (int r = 0; r < 4; ++r) {
        const int qr = wq0 + quad * 4 + r;
        float v[4];
        if (fullvis) {
#pragma unroll
          for (int g = 0; g < 4; ++g) v[g] = sg[g][r] * scale;
        } else {
#pragma unroll
          for (int g = 0; g < 4; ++g) {
            const int krow = kt + g * 16 + l15;
            v[g] = (krow <= qr && krow < SEQ) ? sg[g][r] * scale : NEG;
          }
        }
        float tmax = fmaxf(fmaxf(v[0], v[1]), fmaxf(v[2], v[3]));
#pragma unroll
        for (int off = 1; off < 16; off <<= 1)
          tmax = fmaxf(tmax, __shfl_xor(tmax, off));
        const float mnew = fmaxf(m_i[r], tmax);
        alpha[r] = __expf(m_i[r] - mnew);
        float e[4], rsum = 0.0f;
#pragma unroll
        for (int g = 0; g < 4; ++g) { e[g] = __expf(v[g] - mnew); rsum += e[g]; }
#pragma unroll
        for (int off = 1; off < 16; off <<= 1)
          rsum += __shfl_xor(rsum, off);
        l_i[r] = l_i[r] * alpha[r] + rsum;
        m_i[r] = mnew;
#pragma unroll
        for (int g = 0; g < 4; ++g)
          lPw[(quad * 4 + r) * 72 + g * 16 + l15] = (__bf16)e[g];
      }
#pragma unroll
      for (int nn = 0; nn < 4; ++nn)
#pragma unroll
        for (int r = 0; r < 4; ++r) o[nn][r] *= alpha[r];

      // ---- PV: 2 k-halves x 4 dim-groups = 8 MFMAs, all vector LDS ----
#pragma unroll
      for (int h = 0; h < 2; ++h) {
        const bf16x8 pa = *(const bf16x8*)&lPw[l15 * 72 + h * 32 + quad * 8];
#pragma unroll
        for (int nn = 0; nn < 4; ++nn) {
          const bf16x8 vb =
              *(const bf16x8*)&lV[(nn * 16 + l15) * 72 + h * 32 + quad * 8];
          o[nn] = mfma16(pa, vb, o[nn]);
        }
      }
    }
    __syncthreads();
  }

  const int b = bh >> 4, h = bh & 15;
#pragma unroll
  for (int r = 0; r < 4; ++r) {
    const int qr = wq0 + quad * 4 + r;
    if (qr < SEQ) {
      const float inv = 1.0f / l_i[r];
#pragma unroll
      for (int nn = 0; nn < 4; ++nn) {
        attn[(((size_t)(b * SEQ + qr)) * N_HEAD + h) * D_HEAD + nn * 16 + l15] =
            (__bf16)(o[nn][r] * inv);
      }
    }
  }
}

// ---------------------------------------------------------------------------
// Tiled output projection: out(fp32) = attn(bf16) @ Wo^T(fp32) + bo.
// ---------------------------------------------------------------------------
__global__ __launch_bounds__(256)
void out_gemm(const __bf16* __restrict__ a_in, const float* __restrict__ Wo,
              const float* __restrict__ bo, float* __restrict__ out)
{
  __shared__ __bf16 lA[BM * BK];
  __shared__ __bf16 lB[BN * BK];
  const int mt = blockIdx.x, nt = blockIdx.y;
  const int tid = threadIdx.x;
  const int lane = tid & 63, wave = tid >> 6;
  const int l15 = lane & 15, quad = lane >> 4;
  const int wr = wave >> 1, wc = wave & 1;

  f32x4 acc[4][4] = {};

  for (int k0 = 0; k0 < N_STATE; k0 += BK) {
#pragma unroll
    for (int it = 0; it < 2; ++it) {
      const int s = tid + it * 256;
      const int row = s >> 2, seg = s & 3;
      const int ga = min(mt * BM + row, ROWS - 1);
      *(bf16x8*)&lA[row * BK + seg * 8] =
          *(const bf16x8*)(a_in + (size_t)ga * N_STATE + k0 + seg * 8);
    }
#pragma unroll
    for (int it = 0; it < 4; ++it) {
      const int s = tid + it * 256;
      const int row = s >> 3, seg = s & 7;
      const int gb = nt * BM + row;
      const f32x4 vb = *(const f32x4*)(Wo + (size_t)gb * N_STATE + k0 + seg * 4);
      bf16x4 cb; cb[0]=(__bf16)vb[0]; cb[1]=(__bf16)vb[1];
                 cb[2]=(__bf16)vb[2]; cb[3]=(__bf16)vb[3];
      *(bf16x4*)&lB[row * BK + seg * 4] = cb;
    }
    __syncthreads();
    bf16x8 af[4], bfr[4];
#pragma unroll
    for (int i = 0; i < 4; ++i) {
      af[i]  = *(const bf16x8*)&lA[(wr * 64 + i * 16 + l15) * BK + quad * 8];
      bfr[i] = *(const bf16x8*)&lB[(wc * 64 + i * 16 + l15) * BK + quad * 8];
    }
#pragma unroll
    for (int i = 0; i < 4; ++i)
#pragma unroll
      for (int j = 0; j < 4; ++j)
        acc[i][j] = mfma16(af[i], bfr[j], acc[i][j]);
    __syncthreads();
  }

#pragma unroll
  for (int i = 0; i < 4; ++i) {
    const int mrow = mt * BM + wr * 64 + i * 16 + quad * 4;
#pragma unroll
    for (int j = 0; j < 4; ++j) {
      const int col = nt * BN + wc * 64 + j * 16 + l15;
      const float badd = bo[col];
#pragma unroll
      for (int r = 0; r < 4; ++r) {
        const int row = mrow + r;
        if (row < ROWS)
          out[(size_t)row * N_STATE + col] = acc[i][j][r] + badd;
      }
    }
  }
}

// ---------------------------------------------------------------------------
extern "C" void kernel_launch(void* const* d_in, const int* in_sizes, int n_in,
                              void* d_out, int out_size, void* d_ws, size_t ws_size,
                              hipStream_t stream) {
  const float* x  = (const float*)d_in[0];
  // d_in[1] = mask: causal, implemented analytically — not read.
  const float* Wq = (const float*)d_in[2];
  const float* bq = (const float*)d_in[3];
  const float* Wk = (const float*)d_in[4];
  const float* Wv = (const float*)d_in[5];
  const float* bv = (const float*)d_in[6];
  const float* Wo = (const float*)d_in[7];
  const float* bo = (const float*)d_in[8];
  float* out = (float*)d_out;

  // ws: q [B,H,S,D] + k [B,H,S,D] + v^T [B,H,D,SVP] + attn [B,S,H,D], bf16.
  const size_t chunk = (size_t)ROWS * N_STATE;                 // 12.288M elem
  const size_t vchunk = (size_t)BATCH * N_HEAD * D_HEAD * SVP; // 12.583M elem
  __bf16* q_ws  = (__bf16*)d_ws;
  __bf16* k_ws  = q_ws + chunk;
  __bf16* vt_ws = k_ws + chunk;
  __bf16* attn  = vt_ws + vchunk;

  const int MT = (ROWS + BM - 1) / BM;   // 94
  qkv_gemm<<<dim3(MT, N_STATE / BN, 3), 256, 0, stream>>>(
      x, Wq, bq, Wk, Wv, bv, q_ws, k_ws, vt_ws);
  flash_attn<<<dim3(BATCH * N_HEAD, (SEQ + 63) / 64), 256, 0, stream>>>(
      q_ws, k_ws, vt_ws, attn);
  out_gemm<<<dim3(MT, N_STATE / BN), 256, 0, stream>>>(attn, Wo, bo, out);
}

// Round 7
// 451.669 us; speedup vs baseline: 4.6064x; 1.3343x over previous
//
#include <hip/hip_runtime.h>
#include <hip/hip_bf16.h>

#define N_STATE 1024
#define N_HEAD  16
#define D_HEAD  64
#define BATCH   8
#define SEQ     1500
#define ROWS    (BATCH*SEQ)   // 12000
#define SVP     1536          // padded seq stride for V^T

#define BM 128
#define BN 128
#define BK 32

typedef __bf16 bf16x8 __attribute__((ext_vector_type(8)));
typedef __bf16 bf16x4 __attribute__((ext_vector_type(4)));
typedef float  f32x4  __attribute__((ext_vector_type(4)));

__device__ __forceinline__ f32x4 mfma16(bf16x8 a, bf16x8 b, f32x4 c) {
  return __builtin_amdgcn_mfma_f32_16x16x32_bf16(a, b, c, 0, 0, 0);
}

// Async global->LDS DMA, 16 B/lane. LDS dest is WAVE-UNIFORM base; lane i's
// data lands at dest + i*16 (m104/m108). Global addr is per-lane.
__device__ __forceinline__ void gl_lds16(const void* g, void* l) {
  __builtin_amdgcn_global_load_lds(
      (const __attribute__((address_space(1))) unsigned int*)g,
      (__attribute__((address_space(3))) unsigned int*)l, 16, 0, 0);
}

// ---------------------------------------------------------------------------
// fp32 -> bf16 pre-convert: x -> xb, {Wq,Wk,Wv,Wo} -> wb[4]. Memory-bound.
// ---------------------------------------------------------------------------
__global__ __launch_bounds__(256)
void cvt_all(const float* __restrict__ x,  const float* __restrict__ wq,
             const float* __restrict__ wk, const float* __restrict__ wv,
             const float* __restrict__ wo,
             __bf16* __restrict__ xb, __bf16* __restrict__ wb)
{
  const int which = blockIdx.y;
  const float* src;
  __bf16* dst;
  size_t n;
  if (which == 0) { src = x; dst = xb; n = (size_t)ROWS * N_STATE; }
  else {
    src = (which == 1) ? wq : (which == 2) ? wk : (which == 3) ? wv : wo;
    dst = wb + (size_t)(which - 1) * N_STATE * N_STATE;
    n = (size_t)N_STATE * N_STATE;
  }
  const size_t stride = (size_t)gridDim.x * 256 * 4;
  for (size_t i = ((size_t)blockIdx.x * 256 + threadIdx.x) * 4; i < n; i += stride) {
    const f32x4 v = *(const f32x4*)(src + i);
    bf16x4 c; c[0]=(__bf16)v[0]; c[1]=(__bf16)v[1]; c[2]=(__bf16)v[2]; c[3]=(__bf16)v[3];
    *(bf16x4*)(dst + i) = c;
  }
}

// ---------------------------------------------------------------------------
// FAST QKV projection: pure bf16, m97-style global_load_lds staging.
// Tile 128x128, BK=32, 4 waves. LDS tiles row-major [128][32] bf16; DMA
// slot s (16 B) <-> row=s>>2, seg=s&3; wave w issues slots [w*128, w*128+128).
// which 0/1 (Q,K): normal MFMA, store [B,H,S,D]. which 2 (V): swapped
// operands -> C^T, store [B,H,D,SVP].  (epilogues verbatim from round 6)
// ---------------------------------------------------------------------------
__global__ __launch_bounds__(256)
void qkv_fast(const __bf16* __restrict__ xb, const __bf16* __restrict__ wb,
              const float* __restrict__ bq, const float* __restrict__ bv,
              __bf16* __restrict__ q_ws, __bf16* __restrict__ k_ws,
              __bf16* __restrict__ vt_ws)
{
  __shared__ __bf16 lA[BM * BK];
  __shared__ __bf16 lB[BN * BK];
  const int which = blockIdx.z;
  const __bf16* W = wb + (size_t)which * N_STATE * N_STATE;

  const int mt = blockIdx.x, nt = blockIdx.y;
  const int tid = threadIdx.x;
  const int lane = tid & 63, wave = tid >> 6;
  const int l15 = lane & 15, quad = lane >> 4;
  const int wr = wave >> 1, wc = wave & 1;

  f32x4 acc[4][4] = {};

  for (int k0 = 0; k0 < N_STATE; k0 += BK) {
#pragma unroll
    for (int t = 0; t < 2; ++t) {
      const int c = wave * 2 + t;          // chunk 0..7 (1 KB each)
      const int s = c * 64 + lane;
      const int row = s >> 2, seg = s & 3;
      const int ga = min(mt * BM + row, ROWS - 1);
      gl_lds16(xb + (size_t)ga * N_STATE + k0 + seg * 8, (__bf16*)lA + c * 512);
      const int gb = nt * BN + row;
      gl_lds16(W + (size_t)gb * N_STATE + k0 + seg * 8, (__bf16*)lB + c * 512);
    }
    __syncthreads();
    bf16x8 af[4], bfr[4];
#pragma unroll
    for (int i = 0; i < 4; ++i) {
      af[i]  = *(const bf16x8*)&lA[(wr * 64 + i * 16 + l15) * BK + quad * 8];
      bfr[i] = *(const bf16x8*)&lB[(wc * 64 + i * 16 + l15) * BK + quad * 8];
    }
    if (which != 2) {
#pragma unroll
      for (int i = 0; i < 4; ++i)
#pragma unroll
        for (int j = 0; j < 4; ++j)
          acc[i][j] = mfma16(af[i], bfr[j], acc[i][j]);
    } else {
#pragma unroll
      for (int i = 0; i < 4; ++i)
#pragma unroll
        for (int j = 0; j < 4; ++j)
          acc[i][j] = mfma16(bfr[j], af[i], acc[i][j]);
    }
    __syncthreads();
  }

  if (which != 2) {
#pragma unroll
    for (int i = 0; i < 4; ++i) {
      const int mrow = mt * BM + wr * 64 + i * 16 + quad * 4;
#pragma unroll
      for (int j = 0; j < 4; ++j) {
        const int col = nt * BN + wc * 64 + j * 16 + l15;
        const int h = col >> 6, d = col & 63;
        const float badd = (which == 0) ? bq[col] : 0.0f;
        __bf16* dst = (which == 0) ? q_ws : k_ws;
#pragma unroll
        for (int r = 0; r < 4; ++r) {
          const int row = mrow + r;
          if (row < ROWS) {
            const int b = row / SEQ, s = row % SEQ;
            dst[(((size_t)(b * N_HEAD + h)) * SEQ + s) * D_HEAD + d] =
                (__bf16)(acc[i][j][r] + badd);
          }
        }
      }
    }
  } else {
#pragma unroll
    for (int i = 0; i < 4; ++i) {
      const int sg = mt * BM + wr * 64 + i * 16 + l15;
      const bool valid = sg < ROWS;
      const int b = sg / SEQ, srow = sg % SEQ;
#pragma unroll
      for (int j = 0; j < 4; ++j) {
        const int dbase = nt * BN + wc * 64 + j * 16 + quad * 4;
#pragma unroll
        for (int r = 0; r < 4; ++r) {
          const int d = dbase + r;
          const int h = d >> 6, dd = d & 63;
          if (valid)
            vt_ws[(((size_t)(b * N_HEAD + h)) * D_HEAD + dd) * SVP + srow] =
                (__bf16)(acc[i][j][r] + bv[d]);
        }
      }
    }
  }
}

// ---------------------------------------------------------------------------
// FAST output projection: attn(bf16) @ Wo^T(bf16) + bo -> fp32.
// ---------------------------------------------------------------------------
__global__ __launch_bounds__(256)
void out_fast(const __bf16* __restrict__ a_in, const __bf16* __restrict__ wob,
              const float* __restrict__ bo, float* __restrict__ out)
{
  __shared__ __bf16 lA[BM * BK];
  __shared__ __bf16 lB[BN * BK];
  const int mt = blockIdx.x, nt = blockIdx.y;
  const int tid = threadIdx.x;
  const int lane = tid & 63, wave = tid >> 6;
  const int l15 = lane & 15, quad = lane >> 4;
  const int wr = wave >> 1, wc = wave & 1;

  f32x4 acc[4][4] = {};

  for (int k0 = 0; k0 < N_STATE; k0 += BK) {
#pragma unroll
    for (int t = 0; t < 2; ++t) {
      const int c = wave * 2 + t;
      const int s = c * 64 + lane;
      const int row = s >> 2, seg = s & 3;
      const int ga = min(mt * BM + row, ROWS - 1);
      gl_lds16(a_in + (size_t)ga * N_STATE + k0 + seg * 8, (__bf16*)lA + c * 512);
      const int gb = nt * BN + row;
      gl_lds16(wob + (size_t)gb * N_STATE + k0 + seg * 8, (__bf16*)lB + c * 512);
    }
    __syncthreads();
    bf16x8 af[4], bfr[4];
#pragma unroll
    for (int i = 0; i < 4; ++i) {
      af[i]  = *(const bf16x8*)&lA[(wr * 64 + i * 16 + l15) * BK + quad * 8];
      bfr[i] = *(const bf16x8*)&lB[(wc * 64 + i * 16 + l15) * BK + quad * 8];
    }
#pragma unroll
    for (int i = 0; i < 4; ++i)
#pragma unroll
      for (int j = 0; j < 4; ++j)
        acc[i][j] = mfma16(af[i], bfr[j], acc[i][j]);
    __syncthreads();
  }

#pragma unroll
  for (int i = 0; i < 4; ++i) {
    const int mrow = mt * BM + wr * 64 + i * 16 + quad * 4;
#pragma unroll
    for (int j = 0; j < 4; ++j) {
      const int col = nt * BN + wc * 64 + j * 16 + l15;
      const float badd = bo[col];
#pragma unroll
      for (int r = 0; r < 4; ++r) {
        const int row = mrow + r;
        if (row < ROWS)
          out[(size_t)row * N_STATE + col] = acc[i][j][r] + badd;
      }
    }
  }
}

// ---------------------------------------------------------------------------
// FALLBACK QKV projection (round-6 validated): fp32 in-kernel conversion.
// ---------------------------------------------------------------------------
__global__ __launch_bounds__(256)
void qkv_gemm(const float* __restrict__ x,
              const float* __restrict__ Wq, const float* __restrict__ bq,
              const float* __restrict__ Wk,
              const float* __restrict__ Wv, const float* __restrict__ bv,
              __bf16* __restrict__ q_ws, __bf16* __restrict__ k_ws,
              __bf16* __restrict__ vt_ws)
{
  __shared__ __bf16 lA[BM * BK];
  __shared__ __bf16 lB[BN * BK];
  const int which = blockIdx.z;
  const float* W    = (which == 0) ? Wq : (which == 1) ? Wk : Wv;
  const float* bias = (which == 0) ? bq : (which == 2) ? bv : nullptr;

  const int mt = blockIdx.x, nt = blockIdx.y;
  const int tid = threadIdx.x;
  const int lane = tid & 63, wave = tid >> 6;
  const int l15 = lane & 15, quad = lane >> 4;
  const int wr = wave >> 1, wc = wave & 1;

  f32x4 acc[4][4] = {};

  for (int k0 = 0; k0 < N_STATE; k0 += BK) {
#pragma unroll
    for (int it = 0; it < 4; ++it) {
      const int s = tid + it * 256;
      const int row = s >> 3, seg = s & 7;
      const int ga = min(mt * BM + row, ROWS - 1);
      const f32x4 va = *(const f32x4*)(x + (size_t)ga * N_STATE + k0 + seg * 4);
      bf16x4 ca; ca[0]=(__bf16)va[0]; ca[1]=(__bf16)va[1];
                 ca[2]=(__bf16)va[2]; ca[3]=(__bf16)va[3];
      *(bf16x4*)&lA[row * BK + seg * 4] = ca;
      const int gb = nt * BM + row;
      const f32x4 vb = *(const f32x4*)(W + (size_t)gb * N_STATE + k0 + seg * 4);
      bf16x4 cb; cb[0]=(__bf16)vb[0]; cb[1]=(__bf16)vb[1];
                 cb[2]=(__bf16)vb[2]; cb[3]=(__bf16)vb[3];
      *(bf16x4*)&lB[row * BK + seg * 4] = cb;
    }
    __syncthreads();
    bf16x8 af[4], bfr[4];
#pragma unroll
    for (int i = 0; i < 4; ++i) {
      af[i]  = *(const bf16x8*)&lA[(wr * 64 + i * 16 + l15) * BK + quad * 8];
      bfr[i] = *(const bf16x8*)&lB[(wc * 64 + i * 16 + l15) * BK + quad * 8];
    }
    if (which != 2) {
#pragma unroll
      for (int i = 0; i < 4; ++i)
#pragma unroll
        for (int j = 0; j < 4; ++j)
          acc[i][j] = mfma16(af[i], bfr[j], acc[i][j]);
    } else {
#pragma unroll
      for (int i = 0; i < 4; ++i)
#pragma unroll
        for (int j = 0; j < 4; ++j)
          acc[i][j] = mfma16(bfr[j], af[i], acc[i][j]);
    }
    __syncthreads();
  }

  if (which != 2) {
#pragma unroll
    for (int i = 0; i < 4; ++i) {
      const int mrow = mt * BM + wr * 64 + i * 16 + quad * 4;
#pragma unroll
      for (int j = 0; j < 4; ++j) {
        const int col = nt * BN + wc * 64 + j * 16 + l15;
        const int h = col >> 6, d = col & 63;
        const float badd = bias ? bias[col] : 0.0f;
        __bf16* dst = (which == 0) ? q_ws : k_ws;
#pragma unroll
        for (int r = 0; r < 4; ++r) {
          const int row = mrow + r;
          if (row < ROWS) {
            const int b = row / SEQ, s = row % SEQ;
            dst[(((size_t)(b * N_HEAD + h)) * SEQ + s) * D_HEAD + d] =
                (__bf16)(acc[i][j][r] + badd);
          }
        }
      }
    }
  } else {
#pragma unroll
    for (int i = 0; i < 4; ++i) {
      const int sg = mt * BM + wr * 64 + i * 16 + l15;
      const bool valid = sg < ROWS;
      const int b = sg / SEQ, srow = sg % SEQ;
#pragma unroll
      for (int j = 0; j < 4; ++j) {
        const int dbase = nt * BN + wc * 64 + j * 16 + quad * 4;
#pragma unroll
        for (int r = 0; r < 4; ++r) {
          const int d = dbase + r;
          const int h = d >> 6, dd = d & 63;
          if (valid)
            vt_ws[(((size_t)(b * N_HEAD + h)) * D_HEAD + dd) * SVP + srow] =
                (__bf16)(acc[i][j][r] + bias[d]);
        }
      }
    }
  }
}

// ---------------------------------------------------------------------------
// Flash attention v2, causal — UNCHANGED (validated round 6).
// ---------------------------------------------------------------------------
__global__ __launch_bounds__(256)
void flash_attn(const __bf16* __restrict__ q_ws, const __bf16* __restrict__ k_ws,
                const __bf16* __restrict__ vt_ws, __bf16* __restrict__ attn)
{
  __shared__ __bf16 lK[64 * 72];
  __shared__ __bf16 lV[64 * 72];
  __shared__ __bf16 lP[4 * 16 * 72];
  const int bh = blockIdx.x;
  const int qt = gridDim.y - 1 - blockIdx.y;
  const int tid = threadIdx.x, lane = tid & 63, wave = tid >> 6;
  const int l15 = lane & 15, quad = lane >> 4;
  const __bf16* Q  = q_ws  + (size_t)bh * SEQ * D_HEAD;
  const __bf16* K  = k_ws  + (size_t)bh * SEQ * D_HEAD;
  const __bf16* Vt = vt_ws + (size_t)bh * D_HEAD * SVP;
  __bf16* lPw = lP + wave * 16 * 72;

  const int q0 = qt * 64, wq0 = q0 + wave * 16;
  const int qload = min(wq0 + l15, SEQ - 1);
  const bf16x8 qa0 = *(const bf16x8*)(Q + (size_t)qload * D_HEAD + quad * 8);
  const bf16x8 qa1 = *(const bf16x8*)(Q + (size_t)qload * D_HEAD + 32 + quad * 8);

  const float NEG = -1.0e30f;
  const float scale = 0.125f;
  f32x4 o[4] = {};
  float m_i[4], l_i[4];
#pragma unroll
  for (int r = 0; r < 4; ++r) { m_i[r] = NEG; l_i[r] = 0.0f; }

  const int kmax = min(q0 + 63, SEQ - 1);
  const int wqmax = wq0 + 15;

  for (int kt = 0; kt <= kmax; kt += 64) {
#pragma unroll
    for (int it = 0; it < 2; ++it) {
      const int s = tid + it * 256;
      const int row = s >> 3, seg = s & 7;
      const int gk = min(kt + row, SEQ - 1);
      *(bf16x8*)&lK[row * 72 + seg * 8] =
          *(const bf16x8*)(K + (size_t)gk * D_HEAD + seg * 8);
      *(bf16x8*)&lV[row * 72 + seg * 8] =
          *(const bf16x8*)(Vt + (size_t)row * SVP + kt + seg * 8);
    }
    __syncthreads();

    if (kt <= wqmax) {
      f32x4 sg[4] = {};
#pragma unroll
      for (int g = 0; g < 4; ++g) {
        const __bf16* kr = &lK[(g * 16 + l15) * 72 + quad * 8];
        sg[g] = mfma16(qa0, *(const bf16x8*)kr, sg[g]);
        sg[g] = mfma16(qa1, *(const bf16x8*)(kr + 32), sg[g]);
      }
      const bool fullvis = (kt + 63 <= wq0) && (kt + 63 < SEQ);
      float alpha[4];
#pragma unroll
      for (int r = 0; r < 4; ++r) {
        const int qr = wq0 + quad * 4 + r;
        float v[4];
        if (fullvis) {
#pragma unroll
          for (int g = 0; g < 4; ++g) v[g] = sg[g][r] * scale;
        } else {
#pragma unroll
          for (int g = 0; g < 4; ++g) {
            const int krow = kt + g * 16 + l15;
            v[g] = (krow <= qr && krow < SEQ) ? sg[g][r] * scale : NEG;
          }
        }
        float tmax = fmaxf(fmaxf(v[0], v[1]), fmaxf(v[2], v[3]));
#pragma unroll
        for (int off = 1; off < 16; off <<= 1)
          tmax = fmaxf(tmax, __shfl_xor(tmax, off));
        const float mnew = fmaxf(m_i[r], tmax);
        alpha[r] = __expf(m_i[r] - mnew);
        float e[4], rsum = 0.0f;
#pragma unroll
        for (int g = 0; g < 4; ++g) { e[g] = __expf(v[g] - mnew); rsum += e[g]; }
#pragma unroll
        for (int off = 1; off < 16; off <<= 1)
          rsum += __shfl_xor(rsum, off);
        l_i[r] = l_i[r] * alpha[r] + rsum;
        m_i[r] = mnew;
#pragma unroll
        for (int g = 0; g < 4; ++g)
          lPw[(quad * 4 + r) * 72 + g * 16 + l15] = (__bf16)e[g];
      }
#pragma unroll
      for (int nn = 0; nn < 4; ++nn)
#pragma unroll
        for (int r = 0; r < 4; ++r) o[nn][r] *= alpha[r];

#pragma unroll
      for (int h = 0; h < 2; ++h) {
        const bf16x8 pa = *(const bf16x8*)&lPw[l15 * 72 + h * 32 + quad * 8];
#pragma unroll
        for (int nn = 0; nn < 4; ++nn) {
          const bf16x8 vb =
              *(const bf16x8*)&lV[(nn * 16 + l15) * 72 + h * 32 + quad * 8];
          o[nn] = mfma16(pa, vb, o[nn]);
        }
      }
    }
    __syncthreads();
  }

  const int b = bh >> 4, h = bh & 15;
#pragma unroll
  for (int r = 0; r < 4; ++r) {
    const int qr = wq0 + quad * 4 + r;
    if (qr < SEQ) {
      const float inv = 1.0f / l_i[r];
#pragma unroll
      for (int nn = 0; nn < 4; ++nn) {
        attn[(((size_t)(b * SEQ + qr)) * N_HEAD + h) * D_HEAD + nn * 16 + l15] =
            (__bf16)(o[nn][r] * inv);
      }
    }
  }
}

// ---------------------------------------------------------------------------
// FALLBACK output projection (round-6 validated).
// ---------------------------------------------------------------------------
__global__ __launch_bounds__(256)
void out_gemm(const __bf16* __restrict__ a_in, const float* __restrict__ Wo,
              const float* __restrict__ bo, float* __restrict__ out)
{
  __shared__ __bf16 lA[BM * BK];
  __shared__ __bf16 lB[BN * BK];
  const int mt = blockIdx.x, nt = blockIdx.y;
  const int tid = threadIdx.x;
  const int lane = tid & 63, wave = tid >> 6;
  const int l15 = lane & 15, quad = lane >> 4;
  const int wr = wave >> 1, wc = wave & 1;

  f32x4 acc[4][4] = {};

  for (int k0 = 0; k0 < N_STATE; k0 += BK) {
#pragma unroll
    for (int it = 0; it < 2; ++it) {
      const int s = tid + it * 256;
      const int row = s >> 2, seg = s & 3;
      const int ga = min(mt * BM + row, ROWS - 1);
      *(bf16x8*)&lA[row * BK + seg * 8] =
          *(const bf16x8*)(a_in + (size_t)ga * N_STATE + k0 + seg * 8);
    }
#pragma unroll
    for (int it = 0; it < 4; ++it) {
      const int s = tid + it * 256;
      const int row = s >> 3, seg = s & 7;
      const int gb = nt * BM + row;
      const f32x4 vb = *(const f32x4*)(Wo + (size_t)gb * N_STATE + k0 + seg * 4);
      bf16x4 cb; cb[0]=(__bf16)vb[0]; cb[1]=(__bf16)vb[1];
                 cb[2]=(__bf16)vb[2]; cb[3]=(__bf16)vb[3];
      *(bf16x4*)&lB[row * BK + seg * 4] = cb;
    }
    __syncthreads();
    bf16x8 af[4], bfr[4];
#pragma unroll
    for (int i = 0; i < 4; ++i) {
      af[i]  = *(const bf16x8*)&lA[(wr * 64 + i * 16 + l15) * BK + quad * 8];
      bfr[i] = *(const bf16x8*)&lB[(wc * 64 + i * 16 + l15) * BK + quad * 8];
    }
#pragma unroll
    for (int i = 0; i < 4; ++i)
#pragma unroll
      for (int j = 0; j < 4; ++j)
        acc[i][j] = mfma16(af[i], bfr[j], acc[i][j]);
    __syncthreads();
  }

#pragma unroll
  for (int i = 0; i < 4; ++i) {
    const int mrow = mt * BM + wr * 64 + i * 16 + quad * 4;
#pragma unroll
    for (int j = 0; j < 4; ++j) {
      const int col = nt * BN + wc * 64 + j * 16 + l15;
      const float badd = bo[col];
#pragma unroll
      for (int r = 0; r < 4; ++r) {
        const int row = mrow + r;
        if (row < ROWS)
          out[(size_t)row * N_STATE + col] = acc[i][j][r] + badd;
      }
    }
  }
}

// ---------------------------------------------------------------------------
extern "C" void kernel_launch(void* const* d_in, const int* in_sizes, int n_in,
                              void* d_out, int out_size, void* d_ws, size_t ws_size,
                              hipStream_t stream) {
  const float* x  = (const float*)d_in[0];
  // d_in[1] = mask: causal, implemented analytically — not read.
  const float* Wq = (const float*)d_in[2];
  const float* bq = (const float*)d_in[3];
  const float* Wk = (const float*)d_in[4];
  const float* Wv = (const float*)d_in[5];
  const float* bv = (const float*)d_in[6];
  const float* Wo = (const float*)d_in[7];
  const float* bo = (const float*)d_in[8];
  float* out = (float*)d_out;

  // ws: [q][k][vt][attn|xb][wb]  (xb shares the attn region: qkv finishes
  // reading xb before flash writes attn — stream-ordered).
  const size_t chunk  = (size_t)ROWS * N_STATE;                  // 12.288M
  const size_t vchunk = (size_t)BATCH * N_HEAD * D_HEAD * SVP;   // 12.583M
  const size_t wchunk = (size_t)4 * N_STATE * N_STATE;           //  4.194M
  __bf16* q_ws  = (__bf16*)d_ws;
  __bf16* k_ws  = q_ws + chunk;
  __bf16* vt_ws = k_ws + chunk;
  __bf16* attn  = vt_ws + vchunk;
  __bf16* xb    = attn;                 // overlap
  __bf16* wb    = attn + chunk;
  const size_t need = (3 * chunk + vchunk + wchunk) * sizeof(__bf16);  // 107.3 MB

  const int MT = (ROWS + BM - 1) / BM;   // 94
  if (ws_size >= need) {
    cvt_all<<<dim3(1024, 5), 256, 0, stream>>>(x, Wq, Wk, Wv, Wo, xb, wb);
    qkv_fast<<<dim3(MT, N_STATE / BN, 3), 256, 0, stream>>>(
        xb, wb, bq, bv, q_ws, k_ws, vt_ws);
    flash_attn<<<dim3(BATCH * N_HEAD, (SEQ + 63) / 64), 256, 0, stream>>>(
        q_ws, k_ws, vt_ws, attn);
    out_fast<<<dim3(MT, N_STATE / BN), 256, 0, stream>>>(
        attn, wb + (size_t)3 * N_STATE * N_STATE, bo, out);
  } else {
    qkv_gemm<<<dim3(MT, N_STATE / BN, 3), 256, 0, stream>>>(
        x, Wq, bq, Wk, Wv, bv, q_ws, k_ws, vt_ws);
    flash_attn<<<dim3(BATCH * N_HEAD, (SEQ + 63) / 64), 256, 0, stream>>>(
        q_ws, k_ws, vt_ws, attn);
    out_gemm<<<dim3(MT, N_STATE / BN), 256, 0, stream>>>(attn, Wo, bo, out);
  }
}

// Round 8
// 421.577 us; speedup vs baseline: 4.9352x; 1.0714x over previous
//
#include <hip/hip_runtime.h>
#include <hip/hip_bf16.h>

#define N_STATE 1024
#define N_HEAD  16
#define D_HEAD  64
#define BATCH   8
#define SEQ     1500
#define ROWS    (BATCH*SEQ)   // 12000
#define SVP     1536          // padded seq stride for V^T
#define MTILES  94            // ceil(ROWS/128)

#define BM 128
#define BN 128
#define BK 32

typedef __bf16 bf16x8 __attribute__((ext_vector_type(8)));
typedef __bf16 bf16x4 __attribute__((ext_vector_type(4)));
typedef float  f32x4  __attribute__((ext_vector_type(4)));

__device__ __forceinline__ f32x4 mfma16(bf16x8 a, bf16x8 b, f32x4 c) {
  return __builtin_amdgcn_mfma_f32_16x16x32_bf16(a, b, c, 0, 0, 0);
}

// Async global->LDS DMA, 16 B/lane; LDS dest wave-uniform, lane i -> +i*16.
__device__ __forceinline__ void gl_lds16(const void* g, void* l) {
  __builtin_amdgcn_global_load_lds(
      (const __attribute__((address_space(1))) unsigned int*)g,
      (__attribute__((address_space(3))) unsigned int*)l, 16, 0, 0);
}

// ---------------------------------------------------------------------------
// fp32 -> bf16 pre-convert: x -> xb, {Wq,Wk,Wv,Wo} -> wb[4]. Memory-bound.
// ---------------------------------------------------------------------------
__global__ __launch_bounds__(256)
void cvt_all(const float* __restrict__ x,  const float* __restrict__ wq,
             const float* __restrict__ wk, const float* __restrict__ wv,
             const float* __restrict__ wo,
             __bf16* __restrict__ xb, __bf16* __restrict__ wb)
{
  const int which = blockIdx.y;
  const float* src;
  __bf16* dst;
  size_t n;
  if (which == 0) { src = x; dst = xb; n = (size_t)ROWS * N_STATE; }
  else {
    src = (which == 1) ? wq : (which == 2) ? wk : (which == 3) ? wv : wo;
    dst = wb + (size_t)(which - 1) * N_STATE * N_STATE;
    n = (size_t)N_STATE * N_STATE;
  }
  const size_t stride = (size_t)gridDim.x * 256 * 4;
  for (size_t i = ((size_t)blockIdx.x * 256 + threadIdx.x) * 4; i < n; i += stride) {
    const f32x4 v = *(const f32x4*)(src + i);
    bf16x4 c; c[0]=(__bf16)v[0]; c[1]=(__bf16)v[1]; c[2]=(__bf16)v[2]; c[3]=(__bf16)v[3];
    *(bf16x4*)(dst + i) = c;
  }
}

// ---------------------------------------------------------------------------
// FAST QKV projection: bf16, global_load_lds staging, XOR seg-swizzled LDS
// (slot' = slot ^ ((row>>1)&3)) -> fragment ds_read_b128 is 2-way max (free).
// Grid x encodes XCD-banded tiles: xcd=x&7, j=x>>3, nt=j&7, mt=(j>>3)*8+xcd
// -> per-XCD working set = 12 A-tiles (3 MB) + full W (2 MB), L2-resident.
// which 0/1 (Q,K): store [B,H,S,D]; which 2 (V): swapped ops -> C^T [B,H,D,SVP].
// ---------------------------------------------------------------------------
__global__ __launch_bounds__(256)
void qkv_fast(const __bf16* __restrict__ xb, const __bf16* __restrict__ wb,
              const float* __restrict__ bq, const float* __restrict__ bv,
              __bf16* __restrict__ q_ws, __bf16* __restrict__ k_ws,
              __bf16* __restrict__ vt_ws)
{
  const int xcd = blockIdx.x & 7;
  const int jj  = blockIdx.x >> 3;          // 0..95
  const int nt  = jj & 7;
  const int mt  = (jj >> 3) * 8 + xcd;      // 0..95
  if (mt >= MTILES) return;                 // block-uniform

  __shared__ __bf16 lA[BM * BK];
  __shared__ __bf16 lB[BN * BK];
  const int which = blockIdx.z;
  const __bf16* W = wb + (size_t)which * N_STATE * N_STATE;

  const int tid = threadIdx.x;
  const int lane = tid & 63, wave = tid >> 6;
  const int l15 = lane & 15, quad = lane >> 4;
  const int wr = wave >> 1, wc = wave & 1;

  f32x4 acc[4][4] = {};

  for (int k0 = 0; k0 < N_STATE; k0 += BK) {
#pragma unroll
    for (int t = 0; t < 2; ++t) {
      const int c = wave * 2 + t;           // 1 KB chunk id
      const int s = c * 64 + lane;
      const int row = s >> 2;
      const int sw  = (lane & 3) ^ ((row >> 1) & 3);   // swizzled global seg
      const int ga = min(mt * BM + row, ROWS - 1);
      gl_lds16(xb + (size_t)ga * N_STATE + k0 + sw * 8, (__bf16*)lA + c * 512);
      const int gb = nt * BN + row;
      gl_lds16(W + (size_t)gb * N_STATE + k0 + sw * 8, (__bf16*)lB + c * 512);
    }
    __syncthreads();
    bf16x8 af[4], bfr[4];
#pragma unroll
    for (int i = 0; i < 4; ++i) {
      const int ra = wr * 64 + i * 16 + l15;
      const int rb = wc * 64 + i * 16 + l15;
      af[i]  = *(const bf16x8*)&lA[ra * BK + ((quad ^ ((ra >> 1) & 3)) * 8)];
      bfr[i] = *(const bf16x8*)&lB[rb * BK + ((quad ^ ((rb >> 1) & 3)) * 8)];
    }
    if (which != 2) {
#pragma unroll
      for (int i = 0; i < 4; ++i)
#pragma unroll
        for (int j = 0; j < 4; ++j)
          acc[i][j] = mfma16(af[i], bfr[j], acc[i][j]);
    } else {
#pragma unroll
      for (int i = 0; i < 4; ++i)
#pragma unroll
        for (int j = 0; j < 4; ++j)
          acc[i][j] = mfma16(bfr[j], af[i], acc[i][j]);
    }
    __syncthreads();
  }

  if (which != 2) {
#pragma unroll
    for (int i = 0; i < 4; ++i) {
      const int mrow = mt * BM + wr * 64 + i * 16 + quad * 4;
#pragma unroll
      for (int j = 0; j < 4; ++j) {
        const int col = nt * BN + wc * 64 + j * 16 + l15;
        const int h = col >> 6, d = col & 63;
        const float badd = (which == 0) ? bq[col] : 0.0f;
        __bf16* dst = (which == 0) ? q_ws : k_ws;
#pragma unroll
        for (int r = 0; r < 4; ++r) {
          const int row = mrow + r;
          if (row < ROWS) {
            const int b = row / SEQ, s = row % SEQ;
            dst[(((size_t)(b * N_HEAD + h)) * SEQ + s) * D_HEAD + d] =
                (__bf16)(acc[i][j][r] + badd);
          }
        }
      }
    }
  } else {
#pragma unroll
    for (int i = 0; i < 4; ++i) {
      const int sg = mt * BM + wr * 64 + i * 16 + l15;
      const bool valid = sg < ROWS;
      const int b = sg / SEQ, srow = sg % SEQ;
#pragma unroll
      for (int j = 0; j < 4; ++j) {
        const int dbase = nt * BN + wc * 64 + j * 16 + quad * 4;
#pragma unroll
        for (int r = 0; r < 4; ++r) {
          const int d = dbase + r;
          const int h = d >> 6, dd = d & 63;
          if (valid)
            vt_ws[(((size_t)(b * N_HEAD + h)) * D_HEAD + dd) * SVP + srow] =
                (__bf16)(acc[i][j][r] + bv[d]);
        }
      }
    }
  }
}

// ---------------------------------------------------------------------------
// FAST output projection: attn(bf16) @ Wo^T(bf16) + bo -> fp32.
// Same swizzle + XCD-band mapping.
// ---------------------------------------------------------------------------
__global__ __launch_bounds__(256)
void out_fast(const __bf16* __restrict__ a_in, const __bf16* __restrict__ wob,
              const float* __restrict__ bo, float* __restrict__ out)
{
  const int xcd = blockIdx.x & 7;
  const int jj  = blockIdx.x >> 3;
  const int nt  = jj & 7;
  const int mt  = (jj >> 3) * 8 + xcd;
  if (mt >= MTILES) return;

  __shared__ __bf16 lA[BM * BK];
  __shared__ __bf16 lB[BN * BK];
  const int tid = threadIdx.x;
  const int lane = tid & 63, wave = tid >> 6;
  const int l15 = lane & 15, quad = lane >> 4;
  const int wr = wave >> 1, wc = wave & 1;

  f32x4 acc[4][4] = {};

  for (int k0 = 0; k0 < N_STATE; k0 += BK) {
#pragma unroll
    for (int t = 0; t < 2; ++t) {
      const int c = wave * 2 + t;
      const int s = c * 64 + lane;
      const int row = s >> 2;
      const int sw  = (lane & 3) ^ ((row >> 1) & 3);
      const int ga = min(mt * BM + row, ROWS - 1);
      gl_lds16(a_in + (size_t)ga * N_STATE + k0 + sw * 8, (__bf16*)lA + c * 512);
      const int gb = nt * BN + row;
      gl_lds16(wob + (size_t)gb * N_STATE + k0 + sw * 8, (__bf16*)lB + c * 512);
    }
    __syncthreads();
    bf16x8 af[4], bfr[4];
#pragma unroll
    for (int i = 0; i < 4; ++i) {
      const int ra = wr * 64 + i * 16 + l15;
      const int rb = wc * 64 + i * 16 + l15;
      af[i]  = *(const bf16x8*)&lA[ra * BK + ((quad ^ ((ra >> 1) & 3)) * 8)];
      bfr[i] = *(const bf16x8*)&lB[rb * BK + ((quad ^ ((rb >> 1) & 3)) * 8)];
    }
#pragma unroll
    for (int i = 0; i < 4; ++i)
#pragma unroll
      for (int j = 0; j < 4; ++j)
        acc[i][j] = mfma16(af[i], bfr[j], acc[i][j]);
    __syncthreads();
  }

#pragma unroll
  for (int i = 0; i < 4; ++i) {
    const int mrow = mt * BM + wr * 64 + i * 16 + quad * 4;
#pragma unroll
    for (int j = 0; j < 4; ++j) {
      const int col = nt * BN + wc * 64 + j * 16 + l15;
      const float badd = bo[col];
#pragma unroll
      for (int r = 0; r < 4; ++r) {
        const int row = mrow + r;
        if (row < ROWS)
          out[(size_t)row * N_STATE + col] = acc[i][j][r] + badd;
      }
    }
  }
}

// ---------------------------------------------------------------------------
// FALLBACK QKV projection (round-6 validated): fp32 in-kernel conversion.
// ---------------------------------------------------------------------------
__global__ __launch_bounds__(256)
void qkv_gemm(const float* __restrict__ x,
              const float* __restrict__ Wq, const float* __restrict__ bq,
              const float* __restrict__ Wk,
              const float* __restrict__ Wv, const float* __restrict__ bv,
              __bf16* __restrict__ q_ws, __bf16* __restrict__ k_ws,
              __bf16* __restrict__ vt_ws)
{
  __shared__ __bf16 lA[BM * BK];
  __shared__ __bf16 lB[BN * BK];
  const int which = blockIdx.z;
  const float* W    = (which == 0) ? Wq : (which == 1) ? Wk : Wv;
  const float* bias = (which == 0) ? bq : (which == 2) ? bv : nullptr;

  const int mt = blockIdx.x, nt = blockIdx.y;
  const int tid = threadIdx.x;
  const int lane = tid & 63, wave = tid >> 6;
  const int l15 = lane & 15, quad = lane >> 4;
  const int wr = wave >> 1, wc = wave & 1;

  f32x4 acc[4][4] = {};

  for (int k0 = 0; k0 < N_STATE; k0 += BK) {
#pragma unroll
    for (int it = 0; it < 4; ++it) {
      const int s = tid + it * 256;
      const int row = s >> 3, seg = s & 7;
      const int ga = min(mt * BM + row, ROWS - 1);
      const f32x4 va = *(const f32x4*)(x + (size_t)ga * N_STATE + k0 + seg * 4);
      bf16x4 ca; ca[0]=(__bf16)va[0]; ca[1]=(__bf16)va[1];
                 ca[2]=(__bf16)va[2]; ca[3]=(__bf16)va[3];
      *(bf16x4*)&lA[row * BK + seg * 4] = ca;
      const int gb = nt * BM + row;
      const f32x4 vb = *(const f32x4*)(W + (size_t)gb * N_STATE + k0 + seg * 4);
      bf16x4 cb; cb[0]=(__bf16)vb[0]; cb[1]=(__bf16)vb[1];
                 cb[2]=(__bf16)vb[2]; cb[3]=(__bf16)vb[3];
      *(bf16x4*)&lB[row * BK + seg * 4] = cb;
    }
    __syncthreads();
    bf16x8 af[4], bfr[4];
#pragma unroll
    for (int i = 0; i < 4; ++i) {
      af[i]  = *(const bf16x8*)&lA[(wr * 64 + i * 16 + l15) * BK + quad * 8];
      bfr[i] = *(const bf16x8*)&lB[(wc * 64 + i * 16 + l15) * BK + quad * 8];
    }
    if (which != 2) {
#pragma unroll
      for (int i = 0; i < 4; ++i)
#pragma unroll
        for (int j = 0; j < 4; ++j)
          acc[i][j] = mfma16(af[i], bfr[j], acc[i][j]);
    } else {
#pragma unroll
      for (int i = 0; i < 4; ++i)
#pragma unroll
        for (int j = 0; j < 4; ++j)
          acc[i][j] = mfma16(bfr[j], af[i], acc[i][j]);
    }
    __syncthreads();
  }

  if (which != 2) {
#pragma unroll
    for (int i = 0; i < 4; ++i) {
      const int mrow = mt * BM + wr * 64 + i * 16 + quad * 4;
#pragma unroll
      for (int j = 0; j < 4; ++j) {
        const int col = nt * BN + wc * 64 + j * 16 + l15;
        const int h = col >> 6, d = col & 63;
        const float badd = bias ? bias[col] : 0.0f;
        __bf16* dst = (which == 0) ? q_ws : k_ws;
#pragma unroll
        for (int r = 0; r < 4; ++r) {
          const int row = mrow + r;
          if (row < ROWS) {
            const int b = row / SEQ, s = row % SEQ;
            dst[(((size_t)(b * N_HEAD + h)) * SEQ + s) * D_HEAD + d] =
                (__bf16)(acc[i][j][r] + badd);
          }
        }
      }
    }
  } else {
#pragma unroll
    for (int i = 0; i < 4; ++i) {
      const int sg = mt * BM + wr * 64 + i * 16 + l15;
      const bool valid = sg < ROWS;
      const int b = sg / SEQ, srow = sg % SEQ;
#pragma unroll
      for (int j = 0; j < 4; ++j) {
        const int dbase = nt * BN + wc * 64 + j * 16 + quad * 4;
#pragma unroll
        for (int r = 0; r < 4; ++r) {
          const int d = dbase + r;
          const int h = d >> 6, dd = d & 63;
          if (valid)
            vt_ws[(((size_t)(b * N_HEAD + h)) * D_HEAD + dd) * SVP + srow] =
                (__bf16)(acc[i][j][r] + bias[d]);
        }
      }
    }
  }
}

// ---------------------------------------------------------------------------
// Flash attention v2, causal — UNCHANGED (validated round 6).
// ---------------------------------------------------------------------------
__global__ __launch_bounds__(256)
void flash_attn(const __bf16* __restrict__ q_ws, const __bf16* __restrict__ k_ws,
                const __bf16* __restrict__ vt_ws, __bf16* __restrict__ attn)
{
  __shared__ __bf16 lK[64 * 72];
  __shared__ __bf16 lV[64 * 72];
  __shared__ __bf16 lP[4 * 16 * 72];
  const int bh = blockIdx.x;
  const int qt = gridDim.y - 1 - blockIdx.y;
  const int tid = threadIdx.x, lane = tid & 63, wave = tid >> 6;
  const int l15 = lane & 15, quad = lane >> 4;
  const __bf16* Q  = q_ws  + (size_t)bh * SEQ * D_HEAD;
  const __bf16* K  = k_ws  + (size_t)bh * SEQ * D_HEAD;
  const __bf16* Vt = vt_ws + (size_t)bh * D_HEAD * SVP;
  __bf16* lPw = lP + wave * 16 * 72;

  const int q0 = qt * 64, wq0 = q0 + wave * 16;
  const int qload = min(wq0 + l15, SEQ - 1);
  const bf16x8 qa0 = *(const bf16x8*)(Q + (size_t)qload * D_HEAD + quad * 8);
  const bf16x8 qa1 = *(const bf16x8*)(Q + (size_t)qload * D_HEAD + 32 + quad * 8);

  const float NEG = -1.0e30f;
  const float scale = 0.125f;
  f32x4 o[4] = {};
  float m_i[4], l_i[4];
#pragma unroll
  for (int r = 0; r < 4; ++r) { m_i[r] = NEG; l_i[r] = 0.0f; }

  const int kmax = min(q0 + 63, SEQ - 1);
  const int wqmax = wq0 + 15;

  for (int kt = 0; kt <= kmax; kt += 64) {
#pragma unroll
    for (int it = 0; it < 2; ++it) {
      const int s = tid + it * 256;
      const int row = s >> 3, seg = s & 7;
      const int gk = min(kt + row, SEQ - 1);
      *(bf16x8*)&lK[row * 72 + seg * 8] =
          *(const bf16x8*)(K + (size_t)gk * D_HEAD + seg * 8);
      *(bf16x8*)&lV[row * 72 + seg * 8] =
          *(const bf16x8*)(Vt + (size_t)row * SVP + kt + seg * 8);
    }
    __syncthreads();

    if (kt <= wqmax) {
      f32x4 sg[4] = {};
#pragma unroll
      for (int g = 0; g < 4; ++g) {
        const __bf16* kr = &lK[(g * 16 + l15) * 72 + quad * 8];
        sg[g] = mfma16(qa0, *(const bf16x8*)kr, sg[g]);
        sg[g] = mfma16(qa1, *(const bf16x8*)(kr + 32), sg[g]);
      }
      const bool fullvis = (kt + 63 <= wq0) && (kt + 63 < SEQ);
      float alpha[4];
#pragma unroll
      for (int r = 0; r < 4; ++r) {
        const int qr = wq0 + quad * 4 + r;
        float v[4];
        if (fullvis) {
#pragma unroll
          for (int g = 0; g < 4; ++g) v[g] = sg[g][r] * scale;
        } else {
#pragma unroll
          for (int g = 0; g < 4; ++g) {
            const int krow = kt + g * 16 + l15;
            v[g] = (krow <= qr && krow < SEQ) ? sg[g][r] * scale : NEG;
          }
        }
        float tmax = fmaxf(fmaxf(v[0], v[1]), fmaxf(v[2], v[3]));
#pragma unroll
        for (int off = 1; off < 16; off <<= 1)
          tmax = fmaxf(tmax, __shfl_xor(tmax, off));
        const float mnew = fmaxf(m_i[r], tmax);
        alpha[r] = __expf(m_i[r] - mnew);
        float e[4], rsum = 0.0f;
#pragma unroll
        for (int g = 0; g < 4; ++g) { e[g] = __expf(v[g] - mnew); rsum += e[g]; }
#pragma unroll
        for (int off = 1; off < 16; off <<= 1)
          rsum += __shfl_xor(rsum, off);
        l_i[r] = l_i[r] * alpha[r] + rsum;
        m_i[r] = mnew;
#pragma unroll
        for (int g = 0; g < 4; ++g)
          lPw[(quad * 4 + r) * 72 + g * 16 + l15] = (__bf16)e[g];
      }
#pragma unroll
      for (int nn = 0; nn < 4; ++nn)
#pragma unroll
        for (int r = 0; r < 4; ++r) o[nn][r] *= alpha[r];

#pragma unroll
      for (int h = 0; h < 2; ++h) {
        const bf16x8 pa = *(const bf16x8*)&lPw[l15 * 72 + h * 32 + quad * 8];
#pragma unroll
        for (int nn = 0; nn < 4; ++nn) {
          const bf16x8 vb =
              *(const bf16x8*)&lV[(nn * 16 + l15) * 72 + h * 32 + quad * 8];
          o[nn] = mfma16(pa, vb, o[nn]);
        }
      }
    }
    __syncthreads();
  }

  const int b = bh >> 4, h = bh & 15;
#pragma unroll
  for (int r = 0; r < 4; ++r) {
    const int qr = wq0 + quad * 4 + r;
    if (qr < SEQ) {
      const float inv = 1.0f / l_i[r];
#pragma unroll
      for (int nn = 0; nn < 4; ++nn) {
        attn[(((size_t)(b * SEQ + qr)) * N_HEAD + h) * D_HEAD + nn * 16 + l15] =
            (__bf16)(o[nn][r] * inv);
      }
    }
  }
}

// ---------------------------------------------------------------------------
// FALLBACK output projection (round-6 validated).
// ---------------------------------------------------------------------------
__global__ __launch_bounds__(256)
void out_gemm(const __bf16* __restrict__ a_in, const float* __restrict__ Wo,
              const float* __restrict__ bo, float* __restrict__ out)
{
  __shared__ __bf16 lA[BM * BK];
  __shared__ __bf16 lB[BN * BK];
  const int mt = blockIdx.x, nt = blockIdx.y;
  const int tid = threadIdx.x;
  const int lane = tid & 63, wave = tid >> 6;
  const int l15 = lane & 15, quad = lane >> 4;
  const int wr = wave >> 1, wc = wave & 1;

  f32x4 acc[4][4] = {};

  for (int k0 = 0; k0 < N_STATE; k0 += BK) {
#pragma unroll
    for (int it = 0; it < 2; ++it) {
      const int s = tid + it * 256;
      const int row = s >> 2, seg = s & 3;
      const int ga = min(mt * BM + row, ROWS - 1);
      *(bf16x8*)&lA[row * BK + seg * 8] =
          *(const bf16x8*)(a_in + (size_t)ga * N_STATE + k0 + seg * 8);
    }
#pragma unroll
    for (int it = 0; it < 4; ++it) {
      const int s = tid + it * 256;
      const int row = s >> 3, seg = s & 7;
      const int gb = nt * BM + row;
      const f32x4 vb = *(const f32x4*)(Wo + (size_t)gb * N_STATE + k0 + seg * 4);
      bf16x4 cb; cb[0]=(__bf16)vb[0]; cb[1]=(__bf16)vb[1];
                 cb[2]=(__bf16)vb[2]; cb[3]=(__bf16)vb[3];
      *(bf16x4*)&lB[row * BK + seg * 4] = cb;
    }
    __syncthreads();
    bf16x8 af[4], bfr[4];
#pragma unroll
    for (int i = 0; i < 4; ++i) {
      af[i]  = *(const bf16x8*)&lA[(wr * 64 + i * 16 + l15) * BK + quad * 8];
      bfr[i] = *(const bf16x8*)&lB[(wc * 64 + i * 16 + l15) * BK + quad * 8];
    }
#pragma unroll
    for (int i = 0; i < 4; ++i)
#pragma unroll
      for (int j = 0; j < 4; ++j)
        acc[i][j] = mfma16(af[i], bfr[j], acc[i][j]);
    __syncthreads();
  }

#pragma unroll
  for (int i = 0; i < 4; ++i) {
    const int mrow = mt * BM + wr * 64 + i * 16 + quad * 4;
#pragma unroll
    for (int j = 0; j < 4; ++j) {
      const int col = nt * BN + wc * 64 + j * 16 + l15;
      const float badd = bo[col];
#pragma unroll
      for (int r = 0; r < 4; ++r) {
        const int row = mrow + r;
        if (row < ROWS)
          out[(size_t)row * N_STATE + col] = acc[i][j][r] + badd;
      }
    }
  }
}

// ---------------------------------------------------------------------------
extern "C" void kernel_launch(void* const* d_in, const int* in_sizes, int n_in,
                              void* d_out, int out_size, void* d_ws, size_t ws_size,
                              hipStream_t stream) {
  const float* x  = (const float*)d_in[0];
  // d_in[1] = mask: causal, implemented analytically — not read.
  const float* Wq = (const float*)d_in[2];
  const float* bq = (const float*)d_in[3];
  const float* Wk = (const float*)d_in[4];
  const float* Wv = (const float*)d_in[5];
  const float* bv = (const float*)d_in[6];
  const float* Wo = (const float*)d_in[7];
  const float* bo = (const float*)d_in[8];
  float* out = (float*)d_out;

  // ws: [q][k][vt][attn|xb][wb]  (xb shares the attn region: qkv finishes
  // reading xb before flash writes attn — stream-ordered).
  const size_t chunk  = (size_t)ROWS * N_STATE;                  // 12.288M
  const size_t vchunk = (size_t)BATCH * N_HEAD * D_HEAD * SVP;   // 12.583M
  const size_t wchunk = (size_t)4 * N_STATE * N_STATE;           //  4.194M
  __bf16* q_ws  = (__bf16*)d_ws;
  __bf16* k_ws  = q_ws + chunk;
  __bf16* vt_ws = k_ws + chunk;
  __bf16* attn  = vt_ws + vchunk;
  __bf16* xb    = attn;                 // overlap
  __bf16* wb    = attn + chunk;
  const size_t need = (3 * chunk + vchunk + wchunk) * sizeof(__bf16);  // 107.3 MB

  const int MT = (ROWS + BM - 1) / BM;   // 94
  if (ws_size >= need) {
    cvt_all<<<dim3(1024, 5), 256, 0, stream>>>(x, Wq, Wk, Wv, Wo, xb, wb);
    // grid.x = 768: 12 m-bands x 8 xcd x 8 nt (16 no-op blocks at mt>=94)
    qkv_fast<<<dim3(768, 1, 3), 256, 0, stream>>>(
        xb, wb, bq, bv, q_ws, k_ws, vt_ws);
    flash_attn<<<dim3(BATCH * N_HEAD, (SEQ + 63) / 64), 256, 0, stream>>>(
        q_ws, k_ws, vt_ws, attn);
    out_fast<<<dim3(768, 1, 1), 256, 0, stream>>>(
        attn, wb + (size_t)3 * N_STATE * N_STATE, bo, out);
  } else {
    qkv_gemm<<<dim3(MT, N_STATE / BN, 3), 256, 0, stream>>>(
        x, Wq, bq, Wk, Wv, bv, q_ws, k_ws, vt_ws);
    flash_attn<<<dim3(BATCH * N_HEAD, (SEQ + 63) / 64), 256, 0, stream>>>(
        q_ws, k_ws, vt_ws, attn);
    out_gemm<<<dim3(MT, N_STATE / BN), 256, 0, stream>>>(attn, Wo, bo, out);
  }
}

// Round 9
// 381.906 us; speedup vs baseline: 5.4479x; 1.1039x over previous
//
#include <hip/hip_runtime.h>
#include <hip/hip_bf16.h>

#define N_STATE 1024
#define N_HEAD  16
#define D_HEAD  64
#define BATCH   8
#define SEQ     1500
#define ROWS    (BATCH*SEQ)   // 12000
#define SVP     1536          // padded seq stride for V^T
#define MTILES  94            // ceil(ROWS/128)

#define BM 128
#define BN 128
#define BK 32

typedef __bf16 bf16x8 __attribute__((ext_vector_type(8)));
typedef __bf16 bf16x4 __attribute__((ext_vector_type(4)));
typedef float  f32x4  __attribute__((ext_vector_type(4)));

__device__ __forceinline__ f32x4 mfma16(bf16x8 a, bf16x8 b, f32x4 c) {
  return __builtin_amdgcn_mfma_f32_16x16x32_bf16(a, b, c, 0, 0, 0);
}

// Async global->LDS DMA, 16 B/lane; LDS dest wave-uniform, lane i -> +i*16.
__device__ __forceinline__ void gl_lds16(const void* g, void* l) {
  __builtin_amdgcn_global_load_lds(
      (const __attribute__((address_space(1))) unsigned int*)g,
      (__attribute__((address_space(3))) unsigned int*)l, 16, 0, 0);
}

// ---------------------------------------------------------------------------
// fp32 -> bf16 pre-convert: x -> xb, {Wq,Wk,Wv,Wo} -> wb[4]. Memory-bound.
// ---------------------------------------------------------------------------
__global__ __launch_bounds__(256)
void cvt_all(const float* __restrict__ x,  const float* __restrict__ wq,
             const float* __restrict__ wk, const float* __restrict__ wv,
             const float* __restrict__ wo,
             __bf16* __restrict__ xb, __bf16* __restrict__ wb)
{
  const int which = blockIdx.y;
  const float* src;
  __bf16* dst;
  size_t n;
  if (which == 0) { src = x; dst = xb; n = (size_t)ROWS * N_STATE; }
  else {
    src = (which == 1) ? wq : (which == 2) ? wk : (which == 3) ? wv : wo;
    dst = wb + (size_t)(which - 1) * N_STATE * N_STATE;
    n = (size_t)N_STATE * N_STATE;
  }
  const size_t stride = (size_t)gridDim.x * 256 * 4;
  for (size_t i = ((size_t)blockIdx.x * 256 + threadIdx.x) * 4; i < n; i += stride) {
    const f32x4 v = *(const f32x4*)(src + i);
    bf16x4 c; c[0]=(__bf16)v[0]; c[1]=(__bf16)v[1]; c[2]=(__bf16)v[2]; c[3]=(__bf16)v[3];
    *(bf16x4*)(dst + i) = c;
  }
}

// ---------------------------------------------------------------------------
// FAST QKV projection (validated round 8): bf16, global_load_lds staging,
// XOR seg-swizzled LDS, XCD-banded tile mapping.
// ---------------------------------------------------------------------------
__global__ __launch_bounds__(256)
void qkv_fast(const __bf16* __restrict__ xb, const __bf16* __restrict__ wb,
              const float* __restrict__ bq, const float* __restrict__ bv,
              __bf16* __restrict__ q_ws, __bf16* __restrict__ k_ws,
              __bf16* __restrict__ vt_ws)
{
  const int xcd = blockIdx.x & 7;
  const int jj  = blockIdx.x >> 3;
  const int nt  = jj & 7;
  const int mt  = (jj >> 3) * 8 + xcd;
  if (mt >= MTILES) return;

  __shared__ __bf16 lA[BM * BK];
  __shared__ __bf16 lB[BN * BK];
  const int which = blockIdx.z;
  const __bf16* W = wb + (size_t)which * N_STATE * N_STATE;

  const int tid = threadIdx.x;
  const int lane = tid & 63, wave = tid >> 6;
  const int l15 = lane & 15, quad = lane >> 4;
  const int wr = wave >> 1, wc = wave & 1;

  f32x4 acc[4][4] = {};

  for (int k0 = 0; k0 < N_STATE; k0 += BK) {
#pragma unroll
    for (int t = 0; t < 2; ++t) {
      const int c = wave * 2 + t;
      const int s = c * 64 + lane;
      const int row = s >> 2;
      const int sw  = (lane & 3) ^ ((row >> 1) & 3);
      const int ga = min(mt * BM + row, ROWS - 1);
      gl_lds16(xb + (size_t)ga * N_STATE + k0 + sw * 8, (__bf16*)lA + c * 512);
      const int gb = nt * BN + row;
      gl_lds16(W + (size_t)gb * N_STATE + k0 + sw * 8, (__bf16*)lB + c * 512);
    }
    __syncthreads();
    bf16x8 af[4], bfr[4];
#pragma unroll
    for (int i = 0; i < 4; ++i) {
      const int ra = wr * 64 + i * 16 + l15;
      const int rb = wc * 64 + i * 16 + l15;
      af[i]  = *(const bf16x8*)&lA[ra * BK + ((quad ^ ((ra >> 1) & 3)) * 8)];
      bfr[i] = *(const bf16x8*)&lB[rb * BK + ((quad ^ ((rb >> 1) & 3)) * 8)];
    }
    if (which != 2) {
#pragma unroll
      for (int i = 0; i < 4; ++i)
#pragma unroll
        for (int j = 0; j < 4; ++j)
          acc[i][j] = mfma16(af[i], bfr[j], acc[i][j]);
    } else {
#pragma unroll
      for (int i = 0; i < 4; ++i)
#pragma unroll
        for (int j = 0; j < 4; ++j)
          acc[i][j] = mfma16(bfr[j], af[i], acc[i][j]);
    }
    __syncthreads();
  }

  if (which != 2) {
#pragma unroll
    for (int i = 0; i < 4; ++i) {
      const int mrow = mt * BM + wr * 64 + i * 16 + quad * 4;
#pragma unroll
      for (int j = 0; j < 4; ++j) {
        const int col = nt * BN + wc * 64 + j * 16 + l15;
        const int h = col >> 6, d = col & 63;
        const float badd = (which == 0) ? bq[col] : 0.0f;
        __bf16* dst = (which == 0) ? q_ws : k_ws;
#pragma unroll
        for (int r = 0; r < 4; ++r) {
          const int row = mrow + r;
          if (row < ROWS) {
            const int b = row / SEQ, s = row % SEQ;
            dst[(((size_t)(b * N_HEAD + h)) * SEQ + s) * D_HEAD + d] =
                (__bf16)(acc[i][j][r] + badd);
          }
        }
      }
    }
  } else {
#pragma unroll
    for (int i = 0; i < 4; ++i) {
      const int sg = mt * BM + wr * 64 + i * 16 + l15;
      const bool valid = sg < ROWS;
      const int b = sg / SEQ, srow = sg % SEQ;
#pragma unroll
      for (int j = 0; j < 4; ++j) {
        const int dbase = nt * BN + wc * 64 + j * 16 + quad * 4;
#pragma unroll
        for (int r = 0; r < 4; ++r) {
          const int d = dbase + r;
          const int h = d >> 6, dd = d & 63;
          if (valid)
            vt_ws[(((size_t)(b * N_HEAD + h)) * D_HEAD + dd) * SVP + srow] =
                (__bf16)(acc[i][j][r] + bv[d]);
        }
      }
    }
  }
}

// ---------------------------------------------------------------------------
// FAST output projection (validated round 8).
// ---------------------------------------------------------------------------
__global__ __launch_bounds__(256)
void out_fast(const __bf16* __restrict__ a_in, const __bf16* __restrict__ wob,
              const float* __restrict__ bo, float* __restrict__ out)
{
  const int xcd = blockIdx.x & 7;
  const int jj  = blockIdx.x >> 3;
  const int nt  = jj & 7;
  const int mt  = (jj >> 3) * 8 + xcd;
  if (mt >= MTILES) return;

  __shared__ __bf16 lA[BM * BK];
  __shared__ __bf16 lB[BN * BK];
  const int tid = threadIdx.x;
  const int lane = tid & 63, wave = tid >> 6;
  const int l15 = lane & 15, quad = lane >> 4;
  const int wr = wave >> 1, wc = wave & 1;

  f32x4 acc[4][4] = {};

  for (int k0 = 0; k0 < N_STATE; k0 += BK) {
#pragma unroll
    for (int t = 0; t < 2; ++t) {
      const int c = wave * 2 + t;
      const int s = c * 64 + lane;
      const int row = s >> 2;
      const int sw  = (lane & 3) ^ ((row >> 1) & 3);
      const int ga = min(mt * BM + row, ROWS - 1);
      gl_lds16(a_in + (size_t)ga * N_STATE + k0 + sw * 8, (__bf16*)lA + c * 512);
      const int gb = nt * BN + row;
      gl_lds16(wob + (size_t)gb * N_STATE + k0 + sw * 8, (__bf16*)lB + c * 512);
    }
    __syncthreads();
    bf16x8 af[4], bfr[4];
#pragma unroll
    for (int i = 0; i < 4; ++i) {
      const int ra = wr * 64 + i * 16 + l15;
      const int rb = wc * 64 + i * 16 + l15;
      af[i]  = *(const bf16x8*)&lA[ra * BK + ((quad ^ ((ra >> 1) & 3)) * 8)];
      bfr[i] = *(const bf16x8*)&lB[rb * BK + ((quad ^ ((rb >> 1) & 3)) * 8)];
    }
#pragma unroll
    for (int i = 0; i < 4; ++i)
#pragma unroll
      for (int j = 0; j < 4; ++j)
        acc[i][j] = mfma16(af[i], bfr[j], acc[i][j]);
    __syncthreads();
  }

#pragma unroll
  for (int i = 0; i < 4; ++i) {
    const int mrow = mt * BM + wr * 64 + i * 16 + quad * 4;
#pragma unroll
    for (int j = 0; j < 4; ++j) {
      const int col = nt * BN + wc * 64 + j * 16 + l15;
      const float badd = bo[col];
#pragma unroll
      for (int r = 0; r < 4; ++r) {
        const int row = mrow + r;
        if (row < ROWS)
          out[(size_t)row * N_STATE + col] = acc[i][j][r] + badd;
      }
    }
  }
}

// ---------------------------------------------------------------------------
// FALLBACK QKV projection (round-6 validated).
// ---------------------------------------------------------------------------
__global__ __launch_bounds__(256)
void qkv_gemm(const float* __restrict__ x,
              const float* __restrict__ Wq, const float* __restrict__ bq,
              const float* __restrict__ Wk,
              const float* __restrict__ Wv, const float* __restrict__ bv,
              __bf16* __restrict__ q_ws, __bf16* __restrict__ k_ws,
              __bf16* __restrict__ vt_ws)
{
  __shared__ __bf16 lA[BM * BK];
  __shared__ __bf16 lB[BN * BK];
  const int which = blockIdx.z;
  const float* W    = (which == 0) ? Wq : (which == 1) ? Wk : Wv;
  const float* bias = (which == 0) ? bq : (which == 2) ? bv : nullptr;

  const int mt = blockIdx.x, nt = blockIdx.y;
  const int tid = threadIdx.x;
  const int lane = tid & 63, wave = tid >> 6;
  const int l15 = lane & 15, quad = lane >> 4;
  const int wr = wave >> 1, wc = wave & 1;

  f32x4 acc[4][4] = {};

  for (int k0 = 0; k0 < N_STATE; k0 += BK) {
#pragma unroll
    for (int it = 0; it < 4; ++it) {
      const int s = tid + it * 256;
      const int row = s >> 3, seg = s & 7;
      const int ga = min(mt * BM + row, ROWS - 1);
      const f32x4 va = *(const f32x4*)(x + (size_t)ga * N_STATE + k0 + seg * 4);
      bf16x4 ca; ca[0]=(__bf16)va[0]; ca[1]=(__bf16)va[1];
                 ca[2]=(__bf16)va[2]; ca[3]=(__bf16)va[3];
      *(bf16x4*)&lA[row * BK + seg * 4] = ca;
      const int gb = nt * BM + row;
      const f32x4 vb = *(const f32x4*)(W + (size_t)gb * N_STATE + k0 + seg * 4);
      bf16x4 cb; cb[0]=(__bf16)vb[0]; cb[1]=(__bf16)vb[1];
                 cb[2]=(__bf16)vb[2]; cb[3]=(__bf16)vb[3];
      *(bf16x4*)&lB[row * BK + seg * 4] = cb;
    }
    __syncthreads();
    bf16x8 af[4], bfr[4];
#pragma unroll
    for (int i = 0; i < 4; ++i) {
      af[i]  = *(const bf16x8*)&lA[(wr * 64 + i * 16 + l15) * BK + quad * 8];
      bfr[i] = *(const bf16x8*)&lB[(wc * 64 + i * 16 + l15) * BK + quad * 8];
    }
    if (which != 2) {
#pragma unroll
      for (int i = 0; i < 4; ++i)
#pragma unroll
        for (int j = 0; j < 4; ++j)
          acc[i][j] = mfma16(af[i], bfr[j], acc[i][j]);
    } else {
#pragma unroll
      for (int i = 0; i < 4; ++i)
#pragma unroll
        for (int j = 0; j < 4; ++j)
          acc[i][j] = mfma16(bfr[j], af[i], acc[i][j]);
    }
    __syncthreads();
  }

  if (which != 2) {
#pragma unroll
    for (int i = 0; i < 4; ++i) {
      const int mrow = mt * BM + wr * 64 + i * 16 + quad * 4;
#pragma unroll
      for (int j = 0; j < 4; ++j) {
        const int col = nt * BN + wc * 64 + j * 16 + l15;
        const int h = col >> 6, d = col & 63;
        const float badd = bias ? bias[col] : 0.0f;
        __bf16* dst = (which == 0) ? q_ws : k_ws;
#pragma unroll
        for (int r = 0; r < 4; ++r) {
          const int row = mrow + r;
          if (row < ROWS) {
            const int b = row / SEQ, s = row % SEQ;
            dst[(((size_t)(b * N_HEAD + h)) * SEQ + s) * D_HEAD + d] =
                (__bf16)(acc[i][j][r] + badd);
          }
        }
      }
    }
  } else {
#pragma unroll
    for (int i = 0; i < 4; ++i) {
      const int sg = mt * BM + wr * 64 + i * 16 + l15;
      const bool valid = sg < ROWS;
      const int b = sg / SEQ, srow = sg % SEQ;
#pragma unroll
      for (int j = 0; j < 4; ++j) {
        const int dbase = nt * BN + wc * 64 + j * 16 + quad * 4;
#pragma unroll
        for (int r = 0; r < 4; ++r) {
          const int d = dbase + r;
          const int h = d >> 6, dd = d & 63;
          if (valid)
            vt_ws[(((size_t)(b * N_HEAD + h)) * D_HEAD + dd) * SVP + srow] =
                (__bf16)(acc[i][j][r] + bias[d]);
        }
      }
    }
  }
}

// ---------------------------------------------------------------------------
// Flash attention v3, causal. S^T = K*Q^T so query = lane&15 in C-layout:
// softmax is in-lane (15 VALU max/add) + 2 cross-quad shfls; single m/l/alpha
// per lane. PV computed as O^T = V^T * P^T (A=V-frag, B=P^T-frag) -> output
// col = query too: no alpha transfer, 8B vector stores.
// LDS: lK [8 dim-grp][64 key][8]  (DMA-staged, bank-perfect writes)
//      lV [8 key-grp][64 dim][8]  (DMA-staged)
//      lP per-wave [16 query][72] (b64 VALU writes, b128 B-frag reads)
// ---------------------------------------------------------------------------
__global__ __launch_bounds__(256)
void flash_attn(const __bf16* __restrict__ q_ws, const __bf16* __restrict__ k_ws,
                const __bf16* __restrict__ vt_ws, __bf16* __restrict__ attn)
{
  __shared__ __align__(16) __bf16 lK[8 * 512];
  __shared__ __align__(16) __bf16 lV[8 * 512];
  __shared__ __align__(16) __bf16 lP[4 * 16 * 72];
  const int bh = blockIdx.x;
  const int qt = gridDim.y - 1 - blockIdx.y;   // heavy tiles first
  const int tid = threadIdx.x, lane = tid & 63, wave = tid >> 6;
  const int l15 = lane & 15, quad = lane >> 4;
  const __bf16* Q  = q_ws  + (size_t)bh * SEQ * D_HEAD;
  const __bf16* K  = k_ws  + (size_t)bh * SEQ * D_HEAD;
  const __bf16* Vt = vt_ws + (size_t)bh * D_HEAD * SVP;
  __bf16* lPw = lP + wave * 16 * 72;

  const int q0 = qt * 64, wq0 = q0 + wave * 16;
  const int qload = min(wq0 + l15, SEQ - 1);
  // Q used as the B operand of S^T (B[n=query l15][k=dim quad*8+j]).
  const bf16x8 qa0 = *(const bf16x8*)(Q + (size_t)qload * D_HEAD + quad * 8);
  const bf16x8 qa1 = *(const bf16x8*)(Q + (size_t)qload * D_HEAD + 32 + quad * 8);

  const float NEG = -1.0e30f;
  const float scale = 0.125f;
  const int query = wq0 + l15;
  f32x4 o[4] = {};               // O^T: col=query(l15), row=dim quad*4+r, 4 nn
  float m_i = NEG, l_i = 0.0f;

  const int kmax = min(q0 + 63, SEQ - 1);
  const int wqmax = wq0 + 15;

  for (int kt = 0; kt <= kmax; kt += 64) {
    // ---- DMA staging: chunk c = wave*2+t (8 x 1KB per array) ----
#pragma unroll
    for (int t = 0; t < 2; ++t) {
      const int c = wave * 2 + t;
      // lK chunk c: dim-group c, key row = lane
      const int gk = min(kt + lane, SEQ - 1);
      gl_lds16(K + (size_t)gk * D_HEAD + c * 8, (__bf16*)lK + c * 512);
      // lV chunk c: key-group c, dim row = lane  (pad cols of Vt are finite)
      gl_lds16(Vt + (size_t)lane * SVP + kt + c * 8, (__bf16*)lV + c * 512);
    }
    __syncthreads();

    if (kt <= wqmax) {
      // ---- S^T = K*Q^T: 4 key-groups x 2 dim-halves ----
      f32x4 sg[4] = {};
#pragma unroll
      for (int g = 0; g < 4; ++g) {
        const bf16x8 k0 = *(const bf16x8*)&lK[quad * 512 + (g * 16 + l15) * 8];
        const bf16x8 k1 = *(const bf16x8*)&lK[(4 + quad) * 512 + (g * 16 + l15) * 8];
        sg[g] = mfma16(k0, qa0, sg[g]);
        sg[g] = mfma16(k1, qa1, sg[g]);
      }
      // ---- mask + in-lane softmax (query = l15 column) ----
      const bool fullvis = (kt + 63 <= wq0) && (kt + 63 < SEQ);
      float tmax = NEG;
#pragma unroll
      for (int g = 0; g < 4; ++g)
#pragma unroll
        for (int r = 0; r < 4; ++r) {
          float v = sg[g][r] * scale;
          if (!fullvis) {
            const int key = kt + g * 16 + quad * 4 + r;
            v = (key <= query && key < SEQ) ? v : NEG;
          }
          sg[g][r] = v;
          tmax = fmaxf(tmax, v);
        }
      tmax = fmaxf(tmax, __shfl_xor(tmax, 16));
      tmax = fmaxf(tmax, __shfl_xor(tmax, 32));
      const float mnew = fmaxf(m_i, tmax);
      const float alpha = __expf(m_i - mnew);
      float rsum = 0.0f;
#pragma unroll
      for (int g = 0; g < 4; ++g) {
        bf16x4 pk;
#pragma unroll
        for (int r = 0; r < 4; ++r) {
          const float e = __expf(sg[g][r] - mnew);
          rsum += e;
          pk[r] = (__bf16)e;
        }
        // P^T -> lP[query][key]: keys quad*4+r contiguous -> one b64 write
        *(bf16x4*)&lPw[l15 * 72 + g * 16 + quad * 4] = pk;
      }
      rsum += __shfl_xor(rsum, 16);
      rsum += __shfl_xor(rsum, 32);
      l_i = l_i * alpha + rsum;
      m_i = mnew;
#pragma unroll
      for (int nn = 0; nn < 4; ++nn)
#pragma unroll
        for (int r = 0; r < 4; ++r) o[nn][r] *= alpha;

      // ---- O^T += V^T * P^T  (same-wave LDS write->read, in-order pipe) ----
#pragma unroll
      for (int h = 0; h < 2; ++h) {
        const bf16x8 pb = *(const bf16x8*)&lPw[l15 * 72 + h * 32 + quad * 8];
#pragma unroll
        for (int nn = 0; nn < 4; ++nn) {
          const bf16x8 va =
              *(const bf16x8*)&lV[(h * 4 + quad) * 512 + (nn * 16 + l15) * 8];
          o[nn] = mfma16(va, pb, o[nn]);
        }
      }
    }
    __syncthreads();
  }

  const int b = bh >> 4, hh = bh & 15;
  if (query < SEQ) {
    const float inv = 1.0f / l_i;
#pragma unroll
    for (int nn = 0; nn < 4; ++nn) {
      bf16x4 ov;
#pragma unroll
      for (int r = 0; r < 4; ++r) ov[r] = (__bf16)(o[nn][r] * inv);
      *(bf16x4*)&attn[(((size_t)(b * SEQ + query)) * N_HEAD + hh) * D_HEAD +
                      nn * 16 + quad * 4] = ov;
    }
  }
}

// ---------------------------------------------------------------------------
// FALLBACK output projection (round-6 validated).
// ---------------------------------------------------------------------------
__global__ __launch_bounds__(256)
void out_gemm(const __bf16* __restrict__ a_in, const float* __restrict__ Wo,
              const float* __restrict__ bo, float* __restrict__ out)
{
  __shared__ __bf16 lA[BM * BK];
  __shared__ __bf16 lB[BN * BK];
  const int mt = blockIdx.x, nt = blockIdx.y;
  const int tid = threadIdx.x;
  const int lane = tid & 63, wave = tid >> 6;
  const int l15 = lane & 15, quad = lane >> 4;
  const int wr = wave >> 1, wc = wave & 1;

  f32x4 acc[4][4] = {};

  for (int k0 = 0; k0 < N_STATE; k0 += BK) {
#pragma unroll
    for (int it = 0; it < 2; ++it) {
      const int s = tid + it * 256;
      const int row = s >> 2, seg = s & 3;
      const int ga = min(mt * BM + row, ROWS - 1);
      *(bf16x8*)&lA[row * BK + seg * 8] =
          *(const bf16x8*)(a_in + (size_t)ga * N_STATE + k0 + seg * 8);
    }
#pragma unroll
    for (int it = 0; it < 4; ++it) {
      const int s = tid + it * 256;
      const int row = s >> 3, seg = s & 7;
      const int gb = nt * BM + row;
      const f32x4 vb = *(const f32x4*)(Wo + (size_t)gb * N_STATE + k0 + seg * 4);
      bf16x4 cb; cb[0]=(__bf16)vb[0]; cb[1]=(__bf16)vb[1];
                 cb[2]=(__bf16)vb[2]; cb[3]=(__bf16)vb[3];
      *(bf16x4*)&lB[row * BK + seg * 4] = cb;
    }
    __syncthreads();
    bf16x8 af[4], bfr[4];
#pragma unroll
    for (int i = 0; i < 4; ++i) {
      af[i]  = *(const bf16x8*)&lA[(wr * 64 + i * 16 + l15) * BK + quad * 8];
      bfr[i] = *(const bf16x8*)&lB[(wc * 64 + i * 16 + l15) * BK + quad * 8];
    }
#pragma unroll
    for (int i = 0; i < 4; ++i)
#pragma unroll
      for (int j = 0; j < 4; ++j)
        acc[i][j] = mfma16(af[i], bfr[j], acc[i][j]);
    __syncthreads();
  }

#pragma unroll
  for (int i = 0; i < 4; ++i) {
    const int mrow = mt * BM + wr * 64 + i * 16 + quad * 4;
#pragma unroll
    for (int j = 0; j < 4; ++j) {
      const int col = nt * BN + wc * 64 + j * 16 + l15;
      const float badd = bo[col];
#pragma unroll
      for (int r = 0; r < 4; ++r) {
        const int row = mrow + r;
        if (row < ROWS)
          out[(size_t)row * N_STATE + col] = acc[i][j][r] + badd;
      }
    }
  }
}

// ---------------------------------------------------------------------------
extern "C" void kernel_launch(void* const* d_in, const int* in_sizes, int n_in,
                              void* d_out, int out_size, void* d_ws, size_t ws_size,
                              hipStream_t stream) {
  const float* x  = (const float*)d_in[0];
  // d_in[1] = mask: causal, implemented analytically — not read.
  const float* Wq = (const float*)d_in[2];
  const float* bq = (const float*)d_in[3];
  const float* Wk = (const float*)d_in[4];
  const float* Wv = (const float*)d_in[5];
  const float* bv = (const float*)d_in[6];
  const float* Wo = (const float*)d_in[7];
  const float* bo = (const float*)d_in[8];
  float* out = (float*)d_out;

  // ws: [q][k][vt][attn|xb][wb]  (xb shares the attn region: qkv finishes
  // reading xb before flash writes attn — stream-ordered).
  const size_t chunk  = (size_t)ROWS * N_STATE;                  // 12.288M
  const size_t vchunk = (size_t)BATCH * N_HEAD * D_HEAD * SVP;   // 12.583M
  const size_t wchunk = (size_t)4 * N_STATE * N_STATE;           //  4.194M
  __bf16* q_ws  = (__bf16*)d_ws;
  __bf16* k_ws  = q_ws + chunk;
  __bf16* vt_ws = k_ws + chunk;
  __bf16* attn  = vt_ws + vchunk;
  __bf16* xb    = attn;                 // overlap
  __bf16* wb    = attn + chunk;
  const size_t need = (3 * chunk + vchunk + wchunk) * sizeof(__bf16);  // 107.3 MB

  const int MT = (ROWS + BM - 1) / BM;   // 94
  if (ws_size >= need) {
    cvt_all<<<dim3(1024, 5), 256, 0, stream>>>(x, Wq, Wk, Wv, Wo, xb, wb);
    qkv_fast<<<dim3(768, 1, 3), 256, 0, stream>>>(
        xb, wb, bq, bv, q_ws, k_ws, vt_ws);
    flash_attn<<<dim3(BATCH * N_HEAD, (SEQ + 63) / 64), 256, 0, stream>>>(
        q_ws, k_ws, vt_ws, attn);
    out_fast<<<dim3(768, 1, 1), 256, 0, stream>>>(
        attn, wb + (size_t)3 * N_STATE * N_STATE, bo, out);
  } else {
    qkv_gemm<<<dim3(MT, N_STATE / BN, 3), 256, 0, stream>>>(
        x, Wq, bq, Wk, Wv, bv, q_ws, k_ws, vt_ws);
    flash_attn<<<dim3(BATCH * N_HEAD, (SEQ + 63) / 64), 256, 0, stream>>>(
        q_ws, k_ws, vt_ws, attn);
    out_gemm<<<dim3(MT, N_STATE / BN), 256, 0, stream>>>(attn, Wo, bo, out);
  }
}

// Round 10
// 373.269 us; speedup vs baseline: 5.5739x; 1.0231x over previous
//
#include <hip/hip_runtime.h>
#include <hip/hip_bf16.h>

#define N_STATE 1024
#define N_HEAD  16
#define D_HEAD  64
#define BATCH   8
#define SEQ     1500
#define ROWS    (BATCH*SEQ)   // 12000
#define SVP     1536          // padded seq stride for V^T
#define MTILES  94            // ceil(ROWS/128)

#define BM 128
#define BN 128
#define BK 32     // fallback kernels
#define BK2 64    // fast kernels (round 10)

typedef __bf16 bf16x8 __attribute__((ext_vector_type(8)));
typedef __bf16 bf16x4 __attribute__((ext_vector_type(4)));
typedef float  f32x4  __attribute__((ext_vector_type(4)));

__device__ __forceinline__ f32x4 mfma16(bf16x8 a, bf16x8 b, f32x4 c) {
  return __builtin_amdgcn_mfma_f32_16x16x32_bf16(a, b, c, 0, 0, 0);
}

// Async global->LDS DMA, 16 B/lane; LDS dest wave-uniform, lane i -> +i*16.
__device__ __forceinline__ void gl_lds16(const void* g, void* l) {
  __builtin_amdgcn_global_load_lds(
      (const __attribute__((address_space(1))) unsigned int*)g,
      (__attribute__((address_space(3))) unsigned int*)l, 16, 0, 0);
}

// ---------------------------------------------------------------------------
// fp32 -> bf16 pre-convert: x -> xb, {Wq,Wk,Wv,Wo} -> wb[4]. Memory-bound.
// ---------------------------------------------------------------------------
__global__ __launch_bounds__(256)
void cvt_all(const float* __restrict__ x,  const float* __restrict__ wq,
             const float* __restrict__ wk, const float* __restrict__ wv,
             const float* __restrict__ wo,
             __bf16* __restrict__ xb, __bf16* __restrict__ wb)
{
  const int which = blockIdx.y;
  const float* src;
  __bf16* dst;
  size_t n;
  if (which == 0) { src = x; dst = xb; n = (size_t)ROWS * N_STATE; }
  else {
    src = (which == 1) ? wq : (which == 2) ? wk : (which == 3) ? wv : wo;
    dst = wb + (size_t)(which - 1) * N_STATE * N_STATE;
    n = (size_t)N_STATE * N_STATE;
  }
  const size_t stride = (size_t)gridDim.x * 256 * 4;
  for (size_t i = ((size_t)blockIdx.x * 256 + threadIdx.x) * 4; i < n; i += stride) {
    const f32x4 v = *(const f32x4*)(src + i);
    bf16x4 c; c[0]=(__bf16)v[0]; c[1]=(__bf16)v[1]; c[2]=(__bf16)v[2]; c[3]=(__bf16)v[3];
    *(bf16x4*)(dst + i) = c;
  }
}

// ---------------------------------------------------------------------------
// FAST QKV projection, BK2=64: halves barrier-drain count vs round 9.
// LDS tiles [128][64] bf16 (16 KB each, 32 KB/block — reg-limited occupancy
// unchanged at 2 blocks/CU). DMA chunk c=wave*4+t: slot s=c*64+lane ->
// row=s>>3, seg'=s&7, source seg = seg' ^ (row&7)  (mod-8 XOR swizzle:
// DMA writes bank-perfect; fragment b128 reads 2-way max = free).
// Fragment read (row ra, k-half h): seg' = (h*4+quad) ^ (ra&7).
// which 0/1 (Q,K): store [B,H,S,D]; which 2 (V): swapped ops -> C^T [B,H,D,SVP].
// ---------------------------------------------------------------------------
__global__ __launch_bounds__(256)
void qkv_fast(const __bf16* __restrict__ xb, const __bf16* __restrict__ wb,
              const float* __restrict__ bq, const float* __restrict__ bv,
              __bf16* __restrict__ q_ws, __bf16* __restrict__ k_ws,
              __bf16* __restrict__ vt_ws)
{
  const int xcd = blockIdx.x & 7;
  const int jj  = blockIdx.x >> 3;
  const int nt  = jj & 7;
  const int mt  = (jj >> 3) * 8 + xcd;
  if (mt >= MTILES) return;

  __shared__ __bf16 lA[BM * BK2];
  __shared__ __bf16 lB[BN * BK2];
  const int which = blockIdx.z;
  const __bf16* W = wb + (size_t)which * N_STATE * N_STATE;

  const int tid = threadIdx.x;
  const int lane = tid & 63, wave = tid >> 6;
  const int l15 = lane & 15, quad = lane >> 4;
  const int wr = wave >> 1, wc = wave & 1;

  f32x4 acc[4][4] = {};

  for (int k0 = 0; k0 < N_STATE; k0 += BK2) {
#pragma unroll
    for (int t = 0; t < 4; ++t) {
      const int c = wave * 4 + t;          // 1 KB chunk 0..15
      const int s = c * 64 + lane;
      const int row = s >> 3;
      const int sw  = (lane & 7) ^ (row & 7);   // source seg (8B units)
      const int ga = min(mt * BM + row, ROWS - 1);
      gl_lds16(xb + (size_t)ga * N_STATE + k0 + sw * 8, (__bf16*)lA + c * 512);
      const int gb = nt * BN + row;
      gl_lds16(W + (size_t)gb * N_STATE + k0 + sw * 8, (__bf16*)lB + c * 512);
    }
    __syncthreads();
#pragma unroll
    for (int h = 0; h < 2; ++h) {
      bf16x8 af[4], bfr[4];
#pragma unroll
      for (int i = 0; i < 4; ++i) {
        const int ra = wr * 64 + i * 16 + l15;
        const int rb = wc * 64 + i * 16 + l15;
        af[i]  = *(const bf16x8*)&lA[ra * BK2 + (((h * 4 + quad) ^ (ra & 7)) * 8)];
        bfr[i] = *(const bf16x8*)&lB[rb * BK2 + (((h * 4 + quad) ^ (rb & 7)) * 8)];
      }
      if (which != 2) {
#pragma unroll
        for (int i = 0; i < 4; ++i)
#pragma unroll
          for (int j = 0; j < 4; ++j)
            acc[i][j] = mfma16(af[i], bfr[j], acc[i][j]);
      } else {
#pragma unroll
        for (int i = 0; i < 4; ++i)
#pragma unroll
          for (int j = 0; j < 4; ++j)
            acc[i][j] = mfma16(bfr[j], af[i], acc[i][j]);
      }
    }
    __syncthreads();
  }

  if (which != 2) {
#pragma unroll
    for (int i = 0; i < 4; ++i) {
      const int mrow = mt * BM + wr * 64 + i * 16 + quad * 4;
#pragma unroll
      for (int j = 0; j < 4; ++j) {
        const int col = nt * BN + wc * 64 + j * 16 + l15;
        const int h = col >> 6, d = col & 63;
        const float badd = (which == 0) ? bq[col] : 0.0f;
        __bf16* dst = (which == 0) ? q_ws : k_ws;
#pragma unroll
        for (int r = 0; r < 4; ++r) {
          const int row = mrow + r;
          if (row < ROWS) {
            const int b = row / SEQ, s = row % SEQ;
            dst[(((size_t)(b * N_HEAD + h)) * SEQ + s) * D_HEAD + d] =
                (__bf16)(acc[i][j][r] + badd);
          }
        }
      }
    }
  } else {
#pragma unroll
    for (int i = 0; i < 4; ++i) {
      const int sg = mt * BM + wr * 64 + i * 16 + l15;
      const bool valid = sg < ROWS;
      const int b = sg / SEQ, srow = sg % SEQ;
#pragma unroll
      for (int j = 0; j < 4; ++j) {
        const int dbase = nt * BN + wc * 64 + j * 16 + quad * 4;
#pragma unroll
        for (int r = 0; r < 4; ++r) {
          const int d = dbase + r;
          const int h = d >> 6, dd = d & 63;
          if (valid)
            vt_ws[(((size_t)(b * N_HEAD + h)) * D_HEAD + dd) * SVP + srow] =
                (__bf16)(acc[i][j][r] + bv[d]);
        }
      }
    }
  }
}

// ---------------------------------------------------------------------------
// FAST output projection, BK2=64 (same structure as qkv_fast).
// ---------------------------------------------------------------------------
__global__ __launch_bounds__(256)
void out_fast(const __bf16* __restrict__ a_in, const __bf16* __restrict__ wob,
              const float* __restrict__ bo, float* __restrict__ out)
{
  const int xcd = blockIdx.x & 7;
  const int jj  = blockIdx.x >> 3;
  const int nt  = jj & 7;
  const int mt  = (jj >> 3) * 8 + xcd;
  if (mt >= MTILES) return;

  __shared__ __bf16 lA[BM * BK2];
  __shared__ __bf16 lB[BN * BK2];
  const int tid = threadIdx.x;
  const int lane = tid & 63, wave = tid >> 6;
  const int l15 = lane & 15, quad = lane >> 4;
  const int wr = wave >> 1, wc = wave & 1;

  f32x4 acc[4][4] = {};

  for (int k0 = 0; k0 < N_STATE; k0 += BK2) {
#pragma unroll
    for (int t = 0; t < 4; ++t) {
      const int c = wave * 4 + t;
      const int s = c * 64 + lane;
      const int row = s >> 3;
      const int sw  = (lane & 7) ^ (row & 7);
      const int ga = min(mt * BM + row, ROWS - 1);
      gl_lds16(a_in + (size_t)ga * N_STATE + k0 + sw * 8, (__bf16*)lA + c * 512);
      const int gb = nt * BN + row;
      gl_lds16(wob + (size_t)gb * N_STATE + k0 + sw * 8, (__bf16*)lB + c * 512);
    }
    __syncthreads();
#pragma unroll
    for (int h = 0; h < 2; ++h) {
      bf16x8 af[4], bfr[4];
#pragma unroll
      for (int i = 0; i < 4; ++i) {
        const int ra = wr * 64 + i * 16 + l15;
        const int rb = wc * 64 + i * 16 + l15;
        af[i]  = *(const bf16x8*)&lA[ra * BK2 + (((h * 4 + quad) ^ (ra & 7)) * 8)];
        bfr[i] = *(const bf16x8*)&lB[rb * BK2 + (((h * 4 + quad) ^ (rb & 7)) * 8)];
      }
#pragma unroll
      for (int i = 0; i < 4; ++i)
#pragma unroll
        for (int j = 0; j < 4; ++j)
          acc[i][j] = mfma16(af[i], bfr[j], acc[i][j]);
    }
    __syncthreads();
  }

#pragma unroll
  for (int i = 0; i < 4; ++i) {
    const int mrow = mt * BM + wr * 64 + i * 16 + quad * 4;
#pragma unroll
    for (int j = 0; j < 4; ++j) {
      const int col = nt * BN + wc * 64 + j * 16 + l15;
      const float badd = bo[col];
#pragma unroll
      for (int r = 0; r < 4; ++r) {
        const int row = mrow + r;
        if (row < ROWS)
          out[(size_t)row * N_STATE + col] = acc[i][j][r] + badd;
      }
    }
  }
}

// ---------------------------------------------------------------------------
// FALLBACK QKV projection (round-6 validated).
// ---------------------------------------------------------------------------
__global__ __launch_bounds__(256)
void qkv_gemm(const float* __restrict__ x,
              const float* __restrict__ Wq, const float* __restrict__ bq,
              const float* __restrict__ Wk,
              const float* __restrict__ Wv, const float* __restrict__ bv,
              __bf16* __restrict__ q_ws, __bf16* __restrict__ k_ws,
              __bf16* __restrict__ vt_ws)
{
  __shared__ __bf16 lA[BM * BK];
  __shared__ __bf16 lB[BN * BK];
  const int which = blockIdx.z;
  const float* W    = (which == 0) ? Wq : (which == 1) ? Wk : Wv;
  const float* bias = (which == 0) ? bq : (which == 2) ? bv : nullptr;

  const int mt = blockIdx.x, nt = blockIdx.y;
  const int tid = threadIdx.x;
  const int lane = tid & 63, wave = tid >> 6;
  const int l15 = lane & 15, quad = lane >> 4;
  const int wr = wave >> 1, wc = wave & 1;

  f32x4 acc[4][4] = {};

  for (int k0 = 0; k0 < N_STATE; k0 += BK) {
#pragma unroll
    for (int it = 0; it < 4; ++it) {
      const int s = tid + it * 256;
      const int row = s >> 3, seg = s & 7;
      const int ga = min(mt * BM + row, ROWS - 1);
      const f32x4 va = *(const f32x4*)(x + (size_t)ga * N_STATE + k0 + seg * 4);
      bf16x4 ca; ca[0]=(__bf16)va[0]; ca[1]=(__bf16)va[1];
                 ca[2]=(__bf16)va[2]; ca[3]=(__bf16)va[3];
      *(bf16x4*)&lA[row * BK + seg * 4] = ca;
      const int gb = nt * BM + row;
      const f32x4 vb = *(const f32x4*)(W + (size_t)gb * N_STATE + k0 + seg * 4);
      bf16x4 cb; cb[0]=(__bf16)vb[0]; cb[1]=(__bf16)vb[1];
                 cb[2]=(__bf16)vb[2]; cb[3]=(__bf16)vb[3];
      *(bf16x4*)&lB[row * BK + seg * 4] = cb;
    }
    __syncthreads();
    bf16x8 af[4], bfr[4];
#pragma unroll
    for (int i = 0; i < 4; ++i) {
      af[i]  = *(const bf16x8*)&lA[(wr * 64 + i * 16 + l15) * BK + quad * 8];
      bfr[i] = *(const bf16x8*)&lB[(wc * 64 + i * 16 + l15) * BK + quad * 8];
    }
    if (which != 2) {
#pragma unroll
      for (int i = 0; i < 4; ++i)
#pragma unroll
        for (int j = 0; j < 4; ++j)
          acc[i][j] = mfma16(af[i], bfr[j], acc[i][j]);
    } else {
#pragma unroll
      for (int i = 0; i < 4; ++i)
#pragma unroll
        for (int j = 0; j < 4; ++j)
          acc[i][j] = mfma16(bfr[j], af[i], acc[i][j]);
    }
    __syncthreads();
  }

  if (which != 2) {
#pragma unroll
    for (int i = 0; i < 4; ++i) {
      const int mrow = mt * BM + wr * 64 + i * 16 + quad * 4;
#pragma unroll
      for (int j = 0; j < 4; ++j) {
        const int col = nt * BN + wc * 64 + j * 16 + l15;
        const int h = col >> 6, d = col & 63;
        const float badd = bias ? bias[col] : 0.0f;
        __bf16* dst = (which == 0) ? q_ws : k_ws;
#pragma unroll
        for (int r = 0; r < 4; ++r) {
          const int row = mrow + r;
          if (row < ROWS) {
            const int b = row / SEQ, s = row % SEQ;
            dst[(((size_t)(b * N_HEAD + h)) * SEQ + s) * D_HEAD + d] =
                (__bf16)(acc[i][j][r] + badd);
          }
        }
      }
    }
  } else {
#pragma unroll
    for (int i = 0; i < 4; ++i) {
      const int sg = mt * BM + wr * 64 + i * 16 + l15;
      const bool valid = sg < ROWS;
      const int b = sg / SEQ, srow = sg % SEQ;
#pragma unroll
      for (int j = 0; j < 4; ++j) {
        const int dbase = nt * BN + wc * 64 + j * 16 + quad * 4;
#pragma unroll
        for (int r = 0; r < 4; ++r) {
          const int d = dbase + r;
          const int h = d >> 6, dd = d & 63;
          if (valid)
            vt_ws[(((size_t)(b * N_HEAD + h)) * D_HEAD + dd) * SVP + srow] =
                (__bf16)(acc[i][j][r] + bias[d]);
        }
      }
    }
  }
}

// ---------------------------------------------------------------------------
// Flash attention v3, causal — UNCHANGED (validated round 9).
// ---------------------------------------------------------------------------
__global__ __launch_bounds__(256)
void flash_attn(const __bf16* __restrict__ q_ws, const __bf16* __restrict__ k_ws,
                const __bf16* __restrict__ vt_ws, __bf16* __restrict__ attn)
{
  __shared__ __align__(16) __bf16 lK[8 * 512];
  __shared__ __align__(16) __bf16 lV[8 * 512];
  __shared__ __align__(16) __bf16 lP[4 * 16 * 72];
  const int bh = blockIdx.x;
  const int qt = gridDim.y - 1 - blockIdx.y;
  const int tid = threadIdx.x, lane = tid & 63, wave = tid >> 6;
  const int l15 = lane & 15, quad = lane >> 4;
  const __bf16* Q  = q_ws  + (size_t)bh * SEQ * D_HEAD;
  const __bf16* K  = k_ws  + (size_t)bh * SEQ * D_HEAD;
  const __bf16* Vt = vt_ws + (size_t)bh * D_HEAD * SVP;
  __bf16* lPw = lP + wave * 16 * 72;

  const int q0 = qt * 64, wq0 = q0 + wave * 16;
  const int qload = min(wq0 + l15, SEQ - 1);
  const bf16x8 qa0 = *(const bf16x8*)(Q + (size_t)qload * D_HEAD + quad * 8);
  const bf16x8 qa1 = *(const bf16x8*)(Q + (size_t)qload * D_HEAD + 32 + quad * 8);

  const float NEG = -1.0e30f;
  const float scale = 0.125f;
  const int query = wq0 + l15;
  f32x4 o[4] = {};
  float m_i = NEG, l_i = 0.0f;

  const int kmax = min(q0 + 63, SEQ - 1);
  const int wqmax = wq0 + 15;

  for (int kt = 0; kt <= kmax; kt += 64) {
#pragma unroll
    for (int t = 0; t < 2; ++t) {
      const int c = wave * 2 + t;
      const int gk = min(kt + lane, SEQ - 1);
      gl_lds16(K + (size_t)gk * D_HEAD + c * 8, (__bf16*)lK + c * 512);
      gl_lds16(Vt + (size_t)lane * SVP + kt + c * 8, (__bf16*)lV + c * 512);
    }
    __syncthreads();

    if (kt <= wqmax) {
      f32x4 sg[4] = {};
#pragma unroll
      for (int g = 0; g < 4; ++g) {
        const bf16x8 k0 = *(const bf16x8*)&lK[quad * 512 + (g * 16 + l15) * 8];
        const bf16x8 k1 = *(const bf16x8*)&lK[(4 + quad) * 512 + (g * 16 + l15) * 8];
        sg[g] = mfma16(k0, qa0, sg[g]);
        sg[g] = mfma16(k1, qa1, sg[g]);
      }
      const bool fullvis = (kt + 63 <= wq0) && (kt + 63 < SEQ);
      float tmax = NEG;
#pragma unroll
      for (int g = 0; g < 4; ++g)
#pragma unroll
        for (int r = 0; r < 4; ++r) {
          float v = sg[g][r] * scale;
          if (!fullvis) {
            const int key = kt + g * 16 + quad * 4 + r;
            v = (key <= query && key < SEQ) ? v : NEG;
          }
          sg[g][r] = v;
          tmax = fmaxf(tmax, v);
        }
      tmax = fmaxf(tmax, __shfl_xor(tmax, 16));
      tmax = fmaxf(tmax, __shfl_xor(tmax, 32));
      const float mnew = fmaxf(m_i, tmax);
      const float alpha = __expf(m_i - mnew);
      float rsum = 0.0f;
#pragma unroll
      for (int g = 0; g < 4; ++g) {
        bf16x4 pk;
#pragma unroll
        for (int r = 0; r < 4; ++r) {
          const float e = __expf(sg[g][r] - mnew);
          rsum += e;
          pk[r] = (__bf16)e;
        }
        *(bf16x4*)&lPw[l15 * 72 + g * 16 + quad * 4] = pk;
      }
      rsum += __shfl_xor(rsum, 16);
      rsum += __shfl_xor(rsum, 32);
      l_i = l_i * alpha + rsum;
      m_i = mnew;
#pragma unroll
      for (int nn = 0; nn < 4; ++nn)
#pragma unroll
        for (int r = 0; r < 4; ++r) o[nn][r] *= alpha;

#pragma unroll
      for (int h = 0; h < 2; ++h) {
        const bf16x8 pb = *(const bf16x8*)&lPw[l15 * 72 + h * 32 + quad * 8];
#pragma unroll
        for (int nn = 0; nn < 4; ++nn) {
          const bf16x8 va =
              *(const bf16x8*)&lV[(h * 4 + quad) * 512 + (nn * 16 + l15) * 8];
          o[nn] = mfma16(va, pb, o[nn]);
        }
      }
    }
    __syncthreads();
  }

  const int b = bh >> 4, hh = bh & 15;
  if (query < SEQ) {
    const float inv = 1.0f / l_i;
#pragma unroll
    for (int nn = 0; nn < 4; ++nn) {
      bf16x4 ov;
#pragma unroll
      for (int r = 0; r < 4; ++r) ov[r] = (__bf16)(o[nn][r] * inv);
      *(bf16x4*)&attn[(((size_t)(b * SEQ + query)) * N_HEAD + hh) * D_HEAD +
                      nn * 16 + quad * 4] = ov;
    }
  }
}

// ---------------------------------------------------------------------------
// FALLBACK output projection (round-6 validated).
// ---------------------------------------------------------------------------
__global__ __launch_bounds__(256)
void out_gemm(const __bf16* __restrict__ a_in, const float* __restrict__ Wo,
              const float* __restrict__ bo, float* __restrict__ out)
{
  __shared__ __bf16 lA[BM * BK];
  __shared__ __bf16 lB[BN * BK];
  const int mt = blockIdx.x, nt = blockIdx.y;
  const int tid = threadIdx.x;
  const int lane = tid & 63, wave = tid >> 6;
  const int l15 = lane & 15, quad = lane >> 4;
  const int wr = wave >> 1, wc = wave & 1;

  f32x4 acc[4][4] = {};

  for (int k0 = 0; k0 < N_STATE; k0 += BK) {
#pragma unroll
    for (int it = 0; it < 2; ++it) {
      const int s = tid + it * 256;
      const int row = s >> 2, seg = s & 3;
      const int ga = min(mt * BM + row, ROWS - 1);
      *(bf16x8*)&lA[row * BK + seg * 8] =
          *(const bf16x8*)(a_in + (size_t)ga * N_STATE + k0 + seg * 8);
    }
#pragma unroll
    for (int it = 0; it < 4; ++it) {
      const int s = tid + it * 256;
      const int row = s >> 3, seg = s & 7;
      const int gb = nt * BM + row;
      const f32x4 vb = *(const f32x4*)(Wo + (size_t)gb * N_STATE + k0 + seg * 4);
      bf16x4 cb; cb[0]=(__bf16)vb[0]; cb[1]=(__bf16)vb[1];
                 cb[2]=(__bf16)vb[2]; cb[3]=(__bf16)vb[3];
      *(bf16x4*)&lB[row * BK + seg * 4] = cb;
    }
    __syncthreads();
    bf16x8 af[4], bfr[4];
#pragma unroll
    for (int i = 0; i < 4; ++i) {
      af[i]  = *(const bf16x8*)&lA[(wr * 64 + i * 16 + l15) * BK + quad * 8];
      bfr[i] = *(const bf16x8*)&lB[(wc * 64 + i * 16 + l15) * BK + quad * 8];
    }
#pragma unroll
    for (int i = 0; i < 4; ++i)
#pragma unroll
      for (int j = 0; j < 4; ++j)
        acc[i][j] = mfma16(af[i], bfr[j], acc[i][j]);
    __syncthreads();
  }

#pragma unroll
  for (int i = 0; i < 4; ++i) {
    const int mrow = mt * BM + wr * 64 + i * 16 + quad * 4;
#pragma unroll
    for (int j = 0; j < 4; ++j) {
      const int col = nt * BN + wc * 64 + j * 16 + l15;
      const float badd = bo[col];
#pragma unroll
      for (int r = 0; r < 4; ++r) {
        const int row = mrow + r;
        if (row < ROWS)
          out[(size_t)row * N_STATE + col] = acc[i][j][r] + badd;
      }
    }
  }
}

// ---------------------------------------------------------------------------
extern "C" void kernel_launch(void* const* d_in, const int* in_sizes, int n_in,
                              void* d_out, int out_size, void* d_ws, size_t ws_size,
                              hipStream_t stream) {
  const float* x  = (const float*)d_in[0];
  // d_in[1] = mask: causal, implemented analytically — not read.
  const float* Wq = (const float*)d_in[2];
  const float* bq = (const float*)d_in[3];
  const float* Wk = (const float*)d_in[4];
  const float* Wv = (const float*)d_in[5];
  const float* bv = (const float*)d_in[6];
  const float* Wo = (const float*)d_in[7];
  const float* bo = (const float*)d_in[8];
  float* out = (float*)d_out;

  // ws: [q][k][vt][attn|xb][wb]  (xb shares the attn region: qkv finishes
  // reading xb before flash writes attn — stream-ordered).
  const size_t chunk  = (size_t)ROWS * N_STATE;                  // 12.288M
  const size_t vchunk = (size_t)BATCH * N_HEAD * D_HEAD * SVP;   // 12.583M
  const size_t wchunk = (size_t)4 * N_STATE * N_STATE;           //  4.194M
  __bf16* q_ws  = (__bf16*)d_ws;
  __bf16* k_ws  = q_ws + chunk;
  __bf16* vt_ws = k_ws + chunk;
  __bf16* attn  = vt_ws + vchunk;
  __bf16* xb    = attn;                 // overlap
  __bf16* wb    = attn + chunk;
  const size_t need = (3 * chunk + vchunk + wchunk) * sizeof(__bf16);  // 107.3 MB

  const int MT = (ROWS + BM - 1) / BM;   // 94
  if (ws_size >= need) {
    cvt_all<<<dim3(1024, 5), 256, 0, stream>>>(x, Wq, Wk, Wv, Wo, xb, wb);
    qkv_fast<<<dim3(768, 1, 3), 256, 0, stream>>>(
        xb, wb, bq, bv, q_ws, k_ws, vt_ws);
    flash_attn<<<dim3(BATCH * N_HEAD, (SEQ + 63) / 64), 256, 0, stream>>>(
        q_ws, k_ws, vt_ws, attn);
    out_fast<<<dim3(768, 1, 1), 256, 0, stream>>>(
        attn, wb + (size_t)3 * N_STATE * N_STATE, bo, out);
  } else {
    qkv_gemm<<<dim3(MT, N_STATE / BN, 3), 256, 0, stream>>>(
        x, Wq, bq, Wk, Wv, bv, q_ws, k_ws, vt_ws);
    flash_attn<<<dim3(BATCH * N_HEAD, (SEQ + 63) / 64), 256, 0, stream>>>(
        q_ws, k_ws, vt_ws, attn);
    out_gemm<<<dim3(MT, N_STATE / BN), 256, 0, stream>>>(attn, Wo, bo, out);
  }
}